// Round 1
// baseline (2171.090 us; speedup 1.0000x reference)
//
#include <hip/hip_runtime.h>
#include <cstdint>
#include <cstddef>

#define B_N 4096
#define S_N 64
#define H_N 768
#define L_N 5
#define TEMP_INV (1.0f / 0.07f)
#define BN_EPS 1e-5f

// ---------- block reduction (256 threads = 4 waves of 64) ----------
__device__ inline float block_reduce_sum256(float v, float* sbuf) {
#pragma unroll
  for (int off = 32; off > 0; off >>= 1) v += __shfl_down(v, off, 64);
  int lane = threadIdx.x & 63;
  int wid = threadIdx.x >> 6;
  __syncthreads();  // protect sbuf against previous use
  if (lane == 0) sbuf[wid] = v;
  __syncthreads();
  float r = 0.f;
  if (threadIdx.x == 0) r = sbuf[0] + sbuf[1] + sbuf[2] + sbuf[3];
  return r;  // valid on thread 0 only
}

// ---------- K1: extract z/theta, row L2 norms ----------
__global__ __launch_bounds__(256) void extract_kernel(
    const float* __restrict__ seq, float* __restrict__ zc, float* __restrict__ th,
    float* __restrict__ zn_inv, float* __restrict__ thn_inv) {
  __shared__ float sbuf[4];
  int b = blockIdx.x;
  const float* row = seq + (size_t)b * (S_N * H_N);
  float nrm = 0.f;
  for (int h = threadIdx.x; h < H_N; h += 256) {
    float v = row[h];  // token 0
    zc[(size_t)b * H_N + h] = v;
    nrm += v * v;
  }
  float tot = block_reduce_sum256(nrm, sbuf);
  if (threadIdx.x == 0) zn_inv[b] = 1.f / fmaxf(sqrtf(tot), 1e-12f);
#pragma unroll
  for (int l = 0; l < L_N; ++l) {
    float acc = 0.f;
    for (int h = threadIdx.x; h < H_N; h += 256) {
      float v = (l == 0) ? 0.5f * (row[H_N + h] + row[2 * H_N + h])
                         : row[(size_t)(l + 2) * H_N + h];
      th[((size_t)b * L_N + l) * H_N + h] = v;
      acc += v * v;
    }
    float t = block_reduce_sum256(acc, sbuf);
    if (threadIdx.x == 0) thn_inv[b * L_N + l] = 1.f / fmaxf(sqrtf(t), 1e-12f);
  }
}

// ---------- label histogram ----------
__global__ void count_kernel(const int* __restrict__ labels, int* __restrict__ cnt) {
  int i = blockIdx.x * 256 + threadIdx.x;
  if (i < B_N) atomicAdd(&cnt[labels[i]], 1);
}

// ---------- K2: per-column sum/sumsq ----------
__global__ __launch_bounds__(256) void colstats_kernel(
    const float* __restrict__ X, int rows_per_block, float* __restrict__ sum,
    float* __restrict__ ssq) {
  int r0 = blockIdx.x * rows_per_block;
  int c0 = threadIdx.x, c1 = threadIdx.x + 256, c2 = threadIdx.x + 512;
  float s0 = 0, s1 = 0, s2 = 0, q0 = 0, q1 = 0, q2 = 0;
  for (int r = 0; r < rows_per_block; ++r) {
    const float* row = X + (size_t)(r0 + r) * H_N;
    float v0 = row[c0], v1 = row[c1], v2 = row[c2];
    s0 += v0; q0 += v0 * v0;
    s1 += v1; q1 += v1 * v1;
    s2 += v2; q2 += v2 * v2;
  }
  atomicAdd(&sum[c0], s0); atomicAdd(&ssq[c0], q0);
  atomicAdd(&sum[c1], s1); atomicAdd(&ssq[c1], q1);
  atomicAdd(&sum[c2], s2); atomicAdd(&ssq[c2], q2);
}

// ---------- K3: bn affine coefficients ----------
__global__ void finalize_kernel(
    const float* __restrict__ sum_z, const float* __restrict__ ssq_z,
    const float* __restrict__ sum_t, const float* __restrict__ ssq_t,
    const float* __restrict__ g_z, const float* __restrict__ b_z,
    const float* __restrict__ g_t, const float* __restrict__ b_t,
    float* __restrict__ sz_s, float* __restrict__ sz_t,
    float* __restrict__ st_s, float* __restrict__ st_t) {
  int h = blockIdx.x * 256 + threadIdx.x;
  if (h >= H_N) return;
  {
    float m = sum_z[h] * (1.f / B_N);
    float v = ssq_z[h] * (1.f / B_N) - m * m;
    float s = g_z[h] * rsqrtf(v + BN_EPS);
    sz_s[h] = s;
    sz_t[h] = b_z[h] - m * s;
  }
  {
    float m = sum_t[h] * (1.f / (B_N * L_N));
    float v = ssq_t[h] * (1.f / (B_N * L_N)) - m * m;
    float s = g_t[h] * rsqrtf(v + BN_EPS);
    st_s[h] = s;
    st_t[h] = b_t[h] - m * s;
  }
}

// ---------- K4: zp = bn(z) @ cls_W^T + cls_b  (B^T-form GEMM, column affine on A) ----------
__global__ __launch_bounds__(256) void gemm_zp_kernel(
    const float* __restrict__ A, const float* __restrict__ W /*[N][K]*/,
    const float* __restrict__ sA, const float* __restrict__ tA,
    const float* __restrict__ bias, float* __restrict__ out) {
  __shared__ float As[16][68];
  __shared__ float Bs[16][68];
  int i0 = blockIdx.x * 64, n0 = blockIdx.y * 64;
  int tid = threadIdx.x;
  int tx = tid & 15, ty = tid >> 4;
  int lr = tid >> 4, lc = tid & 15;
  float acc[4][4] = {};
  for (int k0 = 0; k0 < H_N; k0 += 16) {
    float sa = sA[k0 + lc], ta = tA[k0 + lc];
#pragma unroll
    for (int q = 0; q < 4; ++q) {
      int r = lr + q * 16;
      As[lc][r] = A[(size_t)(i0 + r) * H_N + k0 + lc] * sa + ta;
      Bs[lc][r] = W[(size_t)(n0 + r) * H_N + k0 + lc];
    }
    __syncthreads();
#pragma unroll
    for (int k = 0; k < 16; ++k) {
      float4 av = *(const float4*)&As[k][ty * 4];
      float4 bv = *(const float4*)&Bs[k][tx * 4];
      float ar[4] = {av.x, av.y, av.z, av.w};
      float br[4] = {bv.x, bv.y, bv.z, bv.w};
#pragma unroll
      for (int m = 0; m < 4; ++m)
#pragma unroll
        for (int n = 0; n < 4; ++n) acc[m][n] = fmaf(ar[m], br[n], acc[m][n]);
    }
    __syncthreads();
  }
#pragma unroll
  for (int m = 0; m < 4; ++m) {
    int n = n0 + tx * 4;
    float4 o;
    o.x = acc[m][0] + bias[n + 0];
    o.y = acc[m][1] + bias[n + 1];
    o.z = acc[m][2] + bias[n + 2];
    o.w = acc[m][3] + bias[n + 3];
    *(float4*)&out[(size_t)(i0 + ty * 4 + m) * H_N + n] = o;
  }
}

// ---------- K5: u = zp @ label_W  (non-transposed B) ----------
__global__ __launch_bounds__(256) void gemm_u_kernel(
    const float* __restrict__ A, const float* __restrict__ W /*[K][N]*/,
    float* __restrict__ out) {
  __shared__ float As[16][68];
  __shared__ float Bs[16][68];
  int i0 = blockIdx.x * 64, n0 = blockIdx.y * 64;
  int tid = threadIdx.x;
  int tx = tid & 15, ty = tid >> 4;
  int lr = tid >> 4, lc = tid & 15;
  int nn = tid & 63, kk = tid >> 6;
  float acc[4][4] = {};
  for (int k0 = 0; k0 < H_N; k0 += 16) {
#pragma unroll
    for (int q = 0; q < 4; ++q) {
      int r = lr + q * 16;
      As[lc][r] = A[(size_t)(i0 + r) * H_N + k0 + lc];
      Bs[kk + q * 4][nn] = W[(size_t)(k0 + kk + q * 4) * H_N + n0 + nn];
    }
    __syncthreads();
#pragma unroll
    for (int k = 0; k < 16; ++k) {
      float4 av = *(const float4*)&As[k][ty * 4];
      float4 bv = *(const float4*)&Bs[k][tx * 4];
      float ar[4] = {av.x, av.y, av.z, av.w};
      float br[4] = {bv.x, bv.y, bv.z, bv.w};
#pragma unroll
      for (int m = 0; m < 4; ++m)
#pragma unroll
        for (int n = 0; n < 4; ++n) acc[m][n] = fmaf(ar[m], br[n], acc[m][n]);
    }
    __syncthreads();
  }
#pragma unroll
  for (int m = 0; m < 4; ++m) {
    *(float4*)&out[(size_t)(i0 + ty * 4 + m) * H_N + n0 + tx * 4] =
        make_float4(acc[m][0], acc[m][1], acc[m][2], acc[m][3]);
  }
}

// ---------- K6: logits[b,l] = bn(theta)[b,l,:]·u[b,:] + label_b·zp[b,:] ----------
__global__ __launch_bounds__(256) void logits_kernel(
    const float* __restrict__ th, const float* __restrict__ u,
    const float* __restrict__ zp, const float* __restrict__ st_s,
    const float* __restrict__ st_t, const float* __restrict__ label_b,
    float* __restrict__ out) {
  __shared__ float sbuf[4];
  int b = blockIdx.x;
  float p = 0.f;
  for (int h = threadIdx.x; h < H_N; h += 256)
    p += label_b[h] * zp[(size_t)b * H_N + h];
  float lb = block_reduce_sum256(p, sbuf);  // thread 0 only
#pragma unroll
  for (int l = 0; l < L_N; ++l) {
    float acc = 0.f;
    for (int h = threadIdx.x; h < H_N; h += 256) {
      float tb = th[((size_t)b * L_N + l) * H_N + h] * st_s[h] + st_t[h];
      acc += tb * u[(size_t)b * H_N + h];
    }
    float s = block_reduce_sum256(acc, sbuf);
    if (threadIdx.x == 0) out[b * L_N + l] = s + lb;
  }
}

// ---------- K7: big fused GEMM S = z_norm @ theta_norm^T with exp/mask epilogue ----------
__global__ __launch_bounds__(256) void sgemm_fused_kernel(
    const float* __restrict__ zc, const float* __restrict__ th,
    const float* __restrict__ zn_inv, const float* __restrict__ thn_inv,
    const int* __restrict__ labels, float* __restrict__ pos_z,
    float* __restrict__ neg_z, float* __restrict__ pos_t,
    float* __restrict__ neg_t) {
  __shared__ float As[16][68];
  __shared__ float Bs[16][68];
  __shared__ float rpos[64], rneg[64], cpos[64], cneg[64];
  int i0 = blockIdx.x * 64, n0 = blockIdx.y * 64;
  int tid = threadIdx.x;
  int tx = tid & 15, ty = tid >> 4;
  int lr = tid >> 4, lc = tid & 15;
  float ascale[4], bscale[4];
#pragma unroll
  for (int q = 0; q < 4; ++q) {
    ascale[q] = zn_inv[i0 + lr + q * 16];
    bscale[q] = thn_inv[n0 + lr + q * 16];
  }
  float acc[4][4] = {};
  for (int k0 = 0; k0 < H_N; k0 += 16) {
#pragma unroll
    for (int q = 0; q < 4; ++q) {
      int r = lr + q * 16;
      As[lc][r] = zc[(size_t)(i0 + r) * H_N + k0 + lc] * ascale[q];
      Bs[lc][r] = th[(size_t)(n0 + r) * H_N + k0 + lc] * bscale[q];
    }
    __syncthreads();
#pragma unroll
    for (int k = 0; k < 16; ++k) {
      float4 av = *(const float4*)&As[k][ty * 4];
      float4 bv = *(const float4*)&Bs[k][tx * 4];
      float ar[4] = {av.x, av.y, av.z, av.w};
      float br[4] = {bv.x, bv.y, bv.z, bv.w};
#pragma unroll
      for (int m = 0; m < 4; ++m)
#pragma unroll
        for (int n = 0; n < 4; ++n) acc[m][n] = fmaf(ar[m], br[n], acc[m][n]);
    }
    __syncthreads();
  }
  // ---- fused epilogue: exp + masks + row/col reductions ----
  if (tid < 64) { rpos[tid] = 0.f; rneg[tid] = 0.f; cpos[tid] = 0.f; cneg[tid] = 0.f; }
  __syncthreads();
  int ii[4], liv[4];
#pragma unroll
  for (int m = 0; m < 4; ++m) {
    ii[m] = i0 + ty * 4 + m;
    liv[m] = labels[ii[m]];
  }
  int jj[4], llv[4], ljv[4];
#pragma unroll
  for (int n = 0; n < 4; ++n) {
    int nidx = n0 + tx * 4 + n;
    jj[n] = nidx / 5;
    llv[n] = nidx - jj[n] * 5;
    ljv[n] = labels[jj[n]];
  }
  float rp[4] = {}, rn[4] = {}, cp[4] = {}, cn[4] = {};
#pragma unroll
  for (int m = 0; m < 4; ++m) {
#pragma unroll
    for (int n = 0; n < 4; ++n) {
      float e = expf(acc[m][n] * TEMP_INV);
      bool same = (liv[m] == ljv[n]);
      bool diag = (ii[m] == jj[n]);
      if (same) {
        if (!diag && llv[n] == liv[m]) { rp[m] += e; cp[n] += e; }
      } else {
        rn[m] += e;                       // neg_z: all 5 l slices
        if (llv[n] == ljv[n]) cn[n] += e; // neg_t: only l == labels[j]
      }
    }
  }
#pragma unroll
  for (int m = 0; m < 4; ++m) {
    if (rp[m] != 0.f) atomicAdd(&rpos[ty * 4 + m], rp[m]);
    if (rn[m] != 0.f) atomicAdd(&rneg[ty * 4 + m], rn[m]);
  }
#pragma unroll
  for (int n = 0; n < 4; ++n) {
    if (cp[n] != 0.f) atomicAdd(&cpos[tx * 4 + n], cp[n]);
    if (cn[n] != 0.f) atomicAdd(&cneg[tx * 4 + n], cn[n]);
  }
  __syncthreads();
  if (tid < 64) {
    float v;
    v = rpos[tid]; if (v != 0.f) atomicAdd(&pos_z[i0 + tid], v);
    v = rneg[tid]; if (v != 0.f) atomicAdd(&neg_z[i0 + tid], v);
    int j = (n0 + tid) / 5;
    v = cpos[tid]; if (v != 0.f) atomicAdd(&pos_t[j], v);
    v = cneg[tid]; if (v != 0.f) atomicAdd(&neg_t[j], v);
  }
}

// ---------- K8: final loss ----------
__global__ __launch_bounds__(256) void loss_kernel(
    const float* __restrict__ pos_z, const float* __restrict__ neg_z,
    const float* __restrict__ pos_t, const float* __restrict__ neg_t,
    const int* __restrict__ labels, const int* __restrict__ cnt,
    float* __restrict__ out_loss) {
  __shared__ float sbuf[4];
  int i = blockIdx.x * 256 + threadIdx.x;
  float term = 0.f;
  int li = labels[i];
  if (cnt[li] > 1) {
    float pz = pos_z[i], nz = neg_z[i];
    float pt = pos_t[i], nt = neg_t[i];
    term = -logf(pz / (pz + nz + 1e-8f)) - logf(pt / (pt + nt + 1e-8f));
  }
  float s = block_reduce_sum256(term, sbuf);
  if (threadIdx.x == 0) atomicAdd(out_loss, s * (1.0f / B_N));
}

// ---------- launch ----------
extern "C" void kernel_launch(void* const* d_in, const int* in_sizes, int n_in,
                              void* d_out, int out_size, void* d_ws, size_t ws_size,
                              hipStream_t stream) {
  const float* seq = (const float*)d_in[0];
  const float* cls_gamma = (const float*)d_in[1];
  const float* cls_beta = (const float*)d_in[2];
  const float* cls_W = (const float*)d_in[3];
  const float* cls_b = (const float*)d_in[4];
  const float* label_gamma = (const float*)d_in[5];
  const float* label_beta = (const float*)d_in[6];
  const float* label_W = (const float*)d_in[7];
  const float* label_b = (const float*)d_in[8];
  const int* labels = (const int*)d_in[9];
  float* out = (float*)d_out;
  float* ws = (float*)d_ws;

  constexpr size_t OFF_SUMZ = 0;
  constexpr size_t OFF_SSQZ = 768;
  constexpr size_t OFF_SUMT = 1536;
  constexpr size_t OFF_SSQT = 2304;
  constexpr size_t OFF_POSZ = 3072;
  constexpr size_t OFF_NEGZ = 7168;
  constexpr size_t OFF_POST = 11264;
  constexpr size_t OFF_NEGT = 15360;
  constexpr size_t OFF_CNT = 19456;  // 8 ints
  constexpr size_t ZERO_FLOATS = 19464;
  constexpr size_t OFF_SZS = 19464;
  constexpr size_t OFF_SZT = 20232;
  constexpr size_t OFF_STS = 21000;
  constexpr size_t OFF_STT = 21768;
  constexpr size_t OFF_ZNI = 22536;
  constexpr size_t OFF_TNI = 26632;
  constexpr size_t OFF_ZC = 47112;
  constexpr size_t OFF_ZP = OFF_ZC + (size_t)B_N * H_N;
  constexpr size_t OFF_U = OFF_ZP + (size_t)B_N * H_N;
  constexpr size_t OFF_TH = OFF_U + (size_t)B_N * H_N;
  constexpr size_t TOTAL = OFF_TH + (size_t)B_N * L_N * H_N;
  if (ws_size < TOTAL * sizeof(float)) return;  // loud failure rather than corruption

  hipMemsetAsync(d_ws, 0, ZERO_FLOATS * sizeof(float), stream);
  hipMemsetAsync((char*)d_out + (size_t)B_N * L_N * sizeof(float), 0, sizeof(float), stream);

  extract_kernel<<<B_N, 256, 0, stream>>>(seq, ws + OFF_ZC, ws + OFF_TH,
                                          ws + OFF_ZNI, ws + OFF_TNI);
  count_kernel<<<16, 256, 0, stream>>>(labels, (int*)(ws + OFF_CNT));
  colstats_kernel<<<64, 256, 0, stream>>>(ws + OFF_ZC, 64, ws + OFF_SUMZ, ws + OFF_SSQZ);
  colstats_kernel<<<320, 256, 0, stream>>>(ws + OFF_TH, 64, ws + OFF_SUMT, ws + OFF_SSQT);
  finalize_kernel<<<3, 256, 0, stream>>>(
      ws + OFF_SUMZ, ws + OFF_SSQZ, ws + OFF_SUMT, ws + OFF_SSQT, cls_gamma,
      cls_beta, label_gamma, label_beta, ws + OFF_SZS, ws + OFF_SZT,
      ws + OFF_STS, ws + OFF_STT);
  gemm_zp_kernel<<<dim3(64, 12), 256, 0, stream>>>(
      ws + OFF_ZC, cls_W, ws + OFF_SZS, ws + OFF_SZT, cls_b, ws + OFF_ZP);
  gemm_u_kernel<<<dim3(64, 12), 256, 0, stream>>>(ws + OFF_ZP, label_W, ws + OFF_U);
  logits_kernel<<<B_N, 256, 0, stream>>>(ws + OFF_TH, ws + OFF_U, ws + OFF_ZP,
                                         ws + OFF_STS, ws + OFF_STT, label_b, out);
  sgemm_fused_kernel<<<dim3(64, 320), 256, 0, stream>>>(
      ws + OFF_ZC, ws + OFF_TH, ws + OFF_ZNI, ws + OFF_TNI, labels,
      ws + OFF_POSZ, ws + OFF_NEGZ, ws + OFF_POST, ws + OFF_NEGT);
  loss_kernel<<<16, 256, 0, stream>>>(ws + OFF_POSZ, ws + OFF_NEGZ, ws + OFF_POST,
                                      ws + OFF_NEGT, labels,
                                      (const int*)(ws + OFF_CNT),
                                      out + (size_t)B_N * L_N);
}

// Round 2
// 617.771 us; speedup vs baseline: 3.5144x; 3.5144x over previous
//
#include <hip/hip_runtime.h>
#include <hip/hip_bf16.h>
#include <cstdint>
#include <cstddef>

#define B_N 4096
#define S_N 64
#define H_N 768
#define L_N 5
#define TEMP_INV (1.0f / 0.07f)
#define BN_EPS 1e-5f

typedef __attribute__((ext_vector_type(8))) short short8;
typedef __attribute__((ext_vector_type(4))) float f32x4;

// ---------- async global->LDS 16B helper ----------
__device__ __forceinline__ void async_copy16(void* lds, const void* g) {
  __builtin_amdgcn_global_load_lds(
      (const __attribute__((address_space(1))) unsigned int*)g,
      (__attribute__((address_space(3))) unsigned int*)lds, 16, 0, 0);
}

// ---------- block reduction (256 threads = 4 waves of 64) ----------
__device__ inline float block_reduce_sum256(float v, float* sbuf) {
#pragma unroll
  for (int off = 32; off > 0; off >>= 1) v += __shfl_down(v, off, 64);
  int lane = threadIdx.x & 63;
  int wid = threadIdx.x >> 6;
  __syncthreads();
  if (lane == 0) sbuf[wid] = v;
  __syncthreads();
  float r = 0.f;
  if (threadIdx.x == 0) r = sbuf[0] + sbuf[1] + sbuf[2] + sbuf[3];
  return r;  // valid on thread 0 only
}

// ---------- K1: extract z (fp32+bf16), theta (bf16), row inv-norms ----------
__global__ __launch_bounds__(256) void extract_kernel(
    const float* __restrict__ seq, float* __restrict__ zc,
    __hip_bfloat16* __restrict__ zb, __hip_bfloat16* __restrict__ tb,
    float* __restrict__ zn_inv, float* __restrict__ thn_inv) {
  __shared__ float sbuf[4];
  int b = blockIdx.x;
  const float* row = seq + (size_t)b * (S_N * H_N);
  float nrm = 0.f;
  for (int h = threadIdx.x; h < H_N; h += 256) {
    float v = row[h];  // token 0
    zc[(size_t)b * H_N + h] = v;
    zb[(size_t)b * H_N + h] = __float2bfloat16(v);
    nrm += v * v;
  }
  float tot = block_reduce_sum256(nrm, sbuf);
  if (threadIdx.x == 0) zn_inv[b] = 1.f / fmaxf(sqrtf(tot), 1e-12f);
#pragma unroll
  for (int l = 0; l < L_N; ++l) {
    float acc = 0.f;
    for (int h = threadIdx.x; h < H_N; h += 256) {
      float v = (l == 0) ? 0.5f * (row[H_N + h] + row[2 * H_N + h])
                         : row[(size_t)(l + 2) * H_N + h];
      tb[((size_t)b * L_N + l) * H_N + h] = __float2bfloat16(v);
      acc += v * v;
    }
    float t = block_reduce_sum256(acc, sbuf);
    if (threadIdx.x == 0) thn_inv[b * L_N + l] = 1.f / fmaxf(sqrtf(t), 1e-12f);
  }
}

// ---------- label histogram ----------
__global__ void count_kernel(const int* __restrict__ labels, int* __restrict__ cnt) {
  int i = blockIdx.x * 256 + threadIdx.x;
  if (i < B_N) atomicAdd(&cnt[labels[i]], 1);
}

// ---------- K2a: z column stats (reads zc) ----------
__global__ __launch_bounds__(256) void colstats_z_kernel(
    const float* __restrict__ X, float* __restrict__ sum, float* __restrict__ ssq) {
  int r0 = blockIdx.x * 64;
  int c0 = threadIdx.x, c1 = threadIdx.x + 256, c2 = threadIdx.x + 512;
  float s0 = 0, s1 = 0, s2 = 0, q0 = 0, q1 = 0, q2 = 0;
  for (int r = 0; r < 64; ++r) {
    const float* row = X + (size_t)(r0 + r) * H_N;
    float v0 = row[c0], v1 = row[c1], v2 = row[c2];
    s0 += v0; q0 += v0 * v0;
    s1 += v1; q1 += v1 * v1;
    s2 += v2; q2 += v2 * v2;
  }
  atomicAdd(&sum[c0], s0); atomicAdd(&ssq[c0], q0);
  atomicAdd(&sum[c1], s1); atomicAdd(&ssq[c1], q1);
  atomicAdd(&sum[c2], s2); atomicAdd(&ssq[c2], q2);
}

// ---------- K2b: theta column stats (reads seq directly) ----------
__global__ __launch_bounds__(256) void colstats_t_kernel(
    const float* __restrict__ seq, float* __restrict__ sum, float* __restrict__ ssq) {
  int b0 = blockIdx.x * 64;
#pragma unroll
  for (int cc = 0; cc < 3; ++cc) {
    int c = threadIdx.x + cc * 256;
    float s = 0.f, q = 0.f;
    for (int b = 0; b < 64; ++b) {
      const float* base = seq + (size_t)(b0 + b) * (S_N * H_N);
      float v0 = 0.5f * (base[H_N + c] + base[2 * H_N + c]);
      s += v0; q += v0 * v0;
#pragma unroll
      for (int l = 1; l < L_N; ++l) {
        float v = base[(size_t)(l + 2) * H_N + c];
        s += v; q += v * v;
      }
    }
    atomicAdd(&sum[c], s); atomicAdd(&ssq[c], q);
  }
}

// ---------- K3: bn affine coefficients ----------
__global__ void finalize_kernel(
    const float* __restrict__ sum_z, const float* __restrict__ ssq_z,
    const float* __restrict__ sum_t, const float* __restrict__ ssq_t,
    const float* __restrict__ g_z, const float* __restrict__ b_z,
    const float* __restrict__ g_t, const float* __restrict__ b_t,
    float* __restrict__ sz_s, float* __restrict__ sz_t,
    float* __restrict__ st_s, float* __restrict__ st_t) {
  int h = blockIdx.x * 256 + threadIdx.x;
  if (h >= H_N) return;
  {
    float m = sum_z[h] * (1.f / B_N);
    float v = ssq_z[h] * (1.f / B_N) - m * m;
    float s = g_z[h] * rsqrtf(v + BN_EPS);
    sz_s[h] = s;
    sz_t[h] = b_z[h] - m * s;
  }
  {
    float m = sum_t[h] * (1.f / (B_N * L_N));
    float v = ssq_t[h] * (1.f / (B_N * L_N)) - m * m;
    float s = g_t[h] * rsqrtf(v + BN_EPS);
    st_s[h] = s;
    st_t[h] = b_t[h] - m * s;
  }
}

// ---------- K4: zp = bn(z) @ cls_W^T + cls_b ----------
__global__ __launch_bounds__(256) void gemm_zp_kernel(
    const float* __restrict__ A, const float* __restrict__ W /*[N][K]*/,
    const float* __restrict__ sA, const float* __restrict__ tA,
    const float* __restrict__ bias, float* __restrict__ out) {
  __shared__ float As[16][68];
  __shared__ float Bs[16][68];
  int i0 = blockIdx.x * 64, n0 = blockIdx.y * 64;
  int tid = threadIdx.x;
  int tx = tid & 15, ty = tid >> 4;
  int lr = tid >> 4, lc = tid & 15;
  float acc[4][4] = {};
  for (int k0 = 0; k0 < H_N; k0 += 16) {
    float sa = sA[k0 + lc], ta = tA[k0 + lc];
#pragma unroll
    for (int q = 0; q < 4; ++q) {
      int r = lr + q * 16;
      As[lc][r] = A[(size_t)(i0 + r) * H_N + k0 + lc] * sa + ta;
      Bs[lc][r] = W[(size_t)(n0 + r) * H_N + k0 + lc];
    }
    __syncthreads();
#pragma unroll
    for (int k = 0; k < 16; ++k) {
      float4 av = *(const float4*)&As[k][ty * 4];
      float4 bv = *(const float4*)&Bs[k][tx * 4];
      float ar[4] = {av.x, av.y, av.z, av.w};
      float br[4] = {bv.x, bv.y, bv.z, bv.w};
#pragma unroll
      for (int m = 0; m < 4; ++m)
#pragma unroll
        for (int n = 0; n < 4; ++n) acc[m][n] = fmaf(ar[m], br[n], acc[m][n]);
    }
    __syncthreads();
  }
#pragma unroll
  for (int m = 0; m < 4; ++m) {
    int n = n0 + tx * 4;
    float4 o;
    o.x = acc[m][0] + bias[n + 0];
    o.y = acc[m][1] + bias[n + 1];
    o.z = acc[m][2] + bias[n + 2];
    o.w = acc[m][3] + bias[n + 3];
    *(float4*)&out[(size_t)(i0 + ty * 4 + m) * H_N + n] = o;
  }
}

// ---------- K5: u = zp @ label_W ----------
__global__ __launch_bounds__(256) void gemm_u_kernel(
    const float* __restrict__ A, const float* __restrict__ W /*[K][N]*/,
    float* __restrict__ out) {
  __shared__ float As[16][68];
  __shared__ float Bs[16][68];
  int i0 = blockIdx.x * 64, n0 = blockIdx.y * 64;
  int tid = threadIdx.x;
  int tx = tid & 15, ty = tid >> 4;
  int lr = tid >> 4, lc = tid & 15;
  int nn = tid & 63, kk = tid >> 6;
  float acc[4][4] = {};
  for (int k0 = 0; k0 < H_N; k0 += 16) {
#pragma unroll
    for (int q = 0; q < 4; ++q) {
      int r = lr + q * 16;
      As[lc][r] = A[(size_t)(i0 + r) * H_N + k0 + lc];
      Bs[kk + q * 4][nn] = W[(size_t)(k0 + kk + q * 4) * H_N + n0 + nn];
    }
    __syncthreads();
#pragma unroll
    for (int k = 0; k < 16; ++k) {
      float4 av = *(const float4*)&As[k][ty * 4];
      float4 bv = *(const float4*)&Bs[k][tx * 4];
      float ar[4] = {av.x, av.y, av.z, av.w};
      float br[4] = {bv.x, bv.y, bv.z, bv.w};
#pragma unroll
      for (int m = 0; m < 4; ++m)
#pragma unroll
        for (int n = 0; n < 4; ++n) acc[m][n] = fmaf(ar[m], br[n], acc[m][n]);
    }
    __syncthreads();
  }
#pragma unroll
  for (int m = 0; m < 4; ++m) {
    *(float4*)&out[(size_t)(i0 + ty * 4 + m) * H_N + n0 + tx * 4] =
        make_float4(acc[m][0], acc[m][1], acc[m][2], acc[m][3]);
  }
}

// ---------- K6: logits[b,l] = bn(theta)[b,l,:]·u[b,:] + label_b·zp[b,:] ----------
__global__ __launch_bounds__(256) void logits_kernel(
    const float* __restrict__ seq, const float* __restrict__ u,
    const float* __restrict__ zp, const float* __restrict__ st_s,
    const float* __restrict__ st_t, const float* __restrict__ label_b,
    float* __restrict__ out) {
  __shared__ float sbuf[4];
  int b = blockIdx.x;
  const float* base = seq + (size_t)b * (S_N * H_N);
  float p = 0.f;
  for (int h = threadIdx.x; h < H_N; h += 256)
    p += label_b[h] * zp[(size_t)b * H_N + h];
  float lb = block_reduce_sum256(p, sbuf);  // thread 0 only
#pragma unroll
  for (int l = 0; l < L_N; ++l) {
    float acc = 0.f;
    for (int h = threadIdx.x; h < H_N; h += 256) {
      float tv = (l == 0) ? 0.5f * (base[H_N + h] + base[2 * H_N + h])
                          : base[(size_t)(l + 2) * H_N + h];
      float tbn = tv * st_s[h] + st_t[h];
      acc += tbn * u[(size_t)b * H_N + h];
    }
    float s = block_reduce_sum256(acc, sbuf);
    if (threadIdx.x == 0) out[b * L_N + l] = s + lb;
  }
}

// ---------- K7: bf16 MFMA GEMM S = z @ theta^T (raw), fused exp/mask epilogue ----------
// 128x128 tile, 4 waves (2x2), 16x16x32 bf16 MFMA, global_load_lds width-16.
__global__ __launch_bounds__(256) void sgemm_fused_kernel(
    const __hip_bfloat16* __restrict__ zb, const __hip_bfloat16* __restrict__ tb,
    const float* __restrict__ zn_inv, const float* __restrict__ thn_inv,
    const int* __restrict__ labels, float* __restrict__ pos_z,
    float* __restrict__ neg_z, float* __restrict__ pos_t,
    float* __restrict__ neg_t) {
  __shared__ __align__(16) __hip_bfloat16 Asm[128 * 32];
  __shared__ __align__(16) __hip_bfloat16 Bsm[128 * 32];
  __shared__ float rpos[128], rneg[128], cpos[128], cneg[128];
  __shared__ float rnorm[128], cnorm[128];
  __shared__ int rowlab[128], colj[128], coll[128], collab[128];

  int tid = threadIdx.x;
  int lane = tid & 63, wid = tid >> 6;
  int wr = wid >> 1, wc = wid & 1;
  int i0 = blockIdx.x * 128, n0 = blockIdx.y * 128;
  int llo = lane & 15, lhi = lane >> 4;

  f32x4 acc[4][4] = {};

  for (int k0 = 0; k0 < H_N; k0 += 32) {
    // stage A/B tiles: 512 slots of 16B each, 2 rounds of 256 lanes
#pragma unroll
    for (int r = 0; r < 2; ++r) {
      int s = r * 256 + wid * 64 + lane;
      int row = s >> 2, kc = (s & 3) * 8;
      size_t go = (size_t)row * H_N + k0 + kc;
      // wave-uniform LDS base (lane0's slot); HW adds lane*16
      async_copy16((char*)Asm + (size_t)(r * 256 + wid * 64) * 16,
                   zb + (size_t)i0 * H_N + go);
      async_copy16((char*)Bsm + (size_t)(r * 256 + wid * 64) * 16,
                   tb + (size_t)n0 * H_N + go);
    }
    __syncthreads();
    short8 a[4], b[4];
#pragma unroll
    for (int m = 0; m < 4; ++m)
      a[m] = *(const short8*)((const char*)Asm +
                              ((wr * 64 + m * 16 + llo) * 32 + lhi * 8) * 2);
#pragma unroll
    for (int n = 0; n < 4; ++n)
      b[n] = *(const short8*)((const char*)Bsm +
                              ((wc * 64 + n * 16 + llo) * 32 + lhi * 8) * 2);
#pragma unroll
    for (int m = 0; m < 4; ++m)
#pragma unroll
      for (int n = 0; n < 4; ++n)
        acc[m][n] =
            __builtin_amdgcn_mfma_f32_16x16x32_bf16(a[m], b[n], acc[m][n], 0, 0, 0);
    __syncthreads();
  }

  // ---- epilogue meta in LDS ----
  if (tid < 128) {
    rowlab[tid] = labels[i0 + tid];
    rnorm[tid] = zn_inv[i0 + tid] * TEMP_INV;
    int c = n0 + tid;
    int j = c / 5;
    colj[tid] = j;
    coll[tid] = c - j * 5;
    collab[tid] = labels[j];
    cnorm[tid] = thn_inv[c];
    rpos[tid] = 0.f; rneg[tid] = 0.f; cpos[tid] = 0.f; cneg[tid] = 0.f;
  }
  __syncthreads();

  // per-thread column info (4 cols)
  int cl[4], jg[4], lv[4], lj[4];
  float cs[4];
#pragma unroll
  for (int n = 0; n < 4; ++n) {
    cl[n] = wc * 64 + n * 16 + llo;
    jg[n] = colj[cl[n]];
    lv[n] = coll[cl[n]];
    lj[n] = collab[cl[n]];
    cs[n] = cnorm[cl[n]];
  }
  float cpAcc[4] = {}, cnAcc[4] = {};
#pragma unroll
  for (int m = 0; m < 4; ++m) {
#pragma unroll
    for (int r = 0; r < 4; ++r) {
      int rl = wr * 64 + m * 16 + lhi * 4 + r;
      int ig = i0 + rl;
      int li = rowlab[rl];
      float rscale = rnorm[rl];
      float rp = 0.f, rn = 0.f;
#pragma unroll
      for (int n = 0; n < 4; ++n) {
        float e = __expf(acc[m][n][r] * rscale * cs[n]);
        bool same = (li == lj[n]);
        bool diag = (ig == jg[n]);
        if (same) {
          if (!diag && lv[n] == li) { rp += e; cpAcc[n] += e; }
        } else {
          rn += e;
          if (lv[n] == lj[n]) cnAcc[n] += e;
        }
      }
      if (rp != 0.f) atomicAdd(&rpos[rl], rp);
      if (rn != 0.f) atomicAdd(&rneg[rl], rn);
    }
  }
#pragma unroll
  for (int n = 0; n < 4; ++n) {
    if (cpAcc[n] != 0.f) atomicAdd(&cpos[cl[n]], cpAcc[n]);
    if (cnAcc[n] != 0.f) atomicAdd(&cneg[cl[n]], cnAcc[n]);
  }
  __syncthreads();
  if (tid < 128) {
    float v;
    v = rpos[tid]; if (v != 0.f) atomicAdd(&pos_z[i0 + tid], v);
    v = rneg[tid]; if (v != 0.f) atomicAdd(&neg_z[i0 + tid], v);
    int j = colj[tid];
    v = cpos[tid]; if (v != 0.f) atomicAdd(&pos_t[j], v);
    v = cneg[tid]; if (v != 0.f) atomicAdd(&neg_t[j], v);
  }
}

// ---------- K8: final loss ----------
__global__ __launch_bounds__(256) void loss_kernel(
    const float* __restrict__ pos_z, const float* __restrict__ neg_z,
    const float* __restrict__ pos_t, const float* __restrict__ neg_t,
    const int* __restrict__ labels, const int* __restrict__ cnt,
    float* __restrict__ out_loss) {
  __shared__ float sbuf[4];
  int i = blockIdx.x * 256 + threadIdx.x;
  float term = 0.f;
  int li = labels[i];
  if (cnt[li] > 1) {
    float pz = pos_z[i], nz = neg_z[i];
    float pt = pos_t[i], nt = neg_t[i];
    term = -logf(pz / (pz + nz + 1e-8f)) - logf(pt / (pt + nt + 1e-8f));
  }
  float s = block_reduce_sum256(term, sbuf);
  if (threadIdx.x == 0) atomicAdd(out_loss, s * (1.0f / B_N));
}

// ---------- launch ----------
extern "C" void kernel_launch(void* const* d_in, const int* in_sizes, int n_in,
                              void* d_out, int out_size, void* d_ws, size_t ws_size,
                              hipStream_t stream) {
  const float* seq = (const float*)d_in[0];
  const float* cls_gamma = (const float*)d_in[1];
  const float* cls_beta = (const float*)d_in[2];
  const float* cls_W = (const float*)d_in[3];
  const float* cls_b = (const float*)d_in[4];
  const float* label_gamma = (const float*)d_in[5];
  const float* label_beta = (const float*)d_in[6];
  const float* label_W = (const float*)d_in[7];
  const float* label_b = (const float*)d_in[8];
  const int* labels = (const int*)d_in[9];
  float* out = (float*)d_out;
  float* ws = (float*)d_ws;

  constexpr size_t OFF_SUMZ = 0;
  constexpr size_t OFF_SSQZ = 768;
  constexpr size_t OFF_SUMT = 1536;
  constexpr size_t OFF_SSQT = 2304;
  constexpr size_t OFF_POSZ = 3072;
  constexpr size_t OFF_NEGZ = 7168;
  constexpr size_t OFF_POST = 11264;
  constexpr size_t OFF_NEGT = 15360;
  constexpr size_t OFF_CNT = 19456;  // 8 ints
  constexpr size_t ZERO_FLOATS = 19464;
  constexpr size_t OFF_SZS = 19464;
  constexpr size_t OFF_SZT = 20232;
  constexpr size_t OFF_STS = 21000;
  constexpr size_t OFF_STT = 21768;
  constexpr size_t OFF_ZNI = 22536;                 // 4096
  constexpr size_t OFF_TNI = 26632;                 // 20480
  constexpr size_t OFF_ZC = 47112;                  // 4096*768 fp32
  constexpr size_t OFF_ZP = OFF_ZC + (size_t)B_N * H_N;
  constexpr size_t OFF_U = OFF_ZP + (size_t)B_N * H_N;
  constexpr size_t F32_END = OFF_U + (size_t)B_N * H_N;
  constexpr size_t BYTE_ZB = F32_END * sizeof(float);               // 16B aligned
  constexpr size_t BYTE_TB = BYTE_ZB + (size_t)B_N * H_N * 2;       // bf16 z
  constexpr size_t TOTAL_BYTES = BYTE_TB + (size_t)B_N * L_N * H_N * 2;
  if (ws_size < TOTAL_BYTES) return;  // loud failure rather than corruption

  __hip_bfloat16* zb = (__hip_bfloat16*)((char*)d_ws + BYTE_ZB);
  __hip_bfloat16* tb = (__hip_bfloat16*)((char*)d_ws + BYTE_TB);

  hipMemsetAsync(d_ws, 0, ZERO_FLOATS * sizeof(float), stream);
  hipMemsetAsync((char*)d_out + (size_t)B_N * L_N * sizeof(float), 0, sizeof(float),
                 stream);

  extract_kernel<<<B_N, 256, 0, stream>>>(seq, ws + OFF_ZC, zb, tb, ws + OFF_ZNI,
                                          ws + OFF_TNI);
  count_kernel<<<16, 256, 0, stream>>>(labels, (int*)(ws + OFF_CNT));
  colstats_z_kernel<<<64, 256, 0, stream>>>(ws + OFF_ZC, ws + OFF_SUMZ, ws + OFF_SSQZ);
  colstats_t_kernel<<<64, 256, 0, stream>>>(seq, ws + OFF_SUMT, ws + OFF_SSQT);
  finalize_kernel<<<3, 256, 0, stream>>>(
      ws + OFF_SUMZ, ws + OFF_SSQZ, ws + OFF_SUMT, ws + OFF_SSQT, cls_gamma,
      cls_beta, label_gamma, label_beta, ws + OFF_SZS, ws + OFF_SZT, ws + OFF_STS,
      ws + OFF_STT);
  gemm_zp_kernel<<<dim3(64, 12), 256, 0, stream>>>(
      ws + OFF_ZC, cls_W, ws + OFF_SZS, ws + OFF_SZT, cls_b, ws + OFF_ZP);
  gemm_u_kernel<<<dim3(64, 12), 256, 0, stream>>>(ws + OFF_ZP, label_W, ws + OFF_U);
  logits_kernel<<<B_N, 256, 0, stream>>>(seq, ws + OFF_U, ws + OFF_ZP, ws + OFF_STS,
                                         ws + OFF_STT, label_b, out);
  sgemm_fused_kernel<<<dim3(32, 160), 256, 0, stream>>>(
      zb, tb, ws + OFF_ZNI, ws + OFF_TNI, labels, ws + OFF_POSZ, ws + OFF_NEGZ,
      ws + OFF_POST, ws + OFF_NEGT);
  loss_kernel<<<16, 256, 0, stream>>>(ws + OFF_POSZ, ws + OFF_NEGZ, ws + OFF_POST,
                                      ws + OFF_NEGT, labels,
                                      (const int*)(ws + OFF_CNT),
                                      out + (size_t)B_N * L_N);
}

// Round 3
// 502.569 us; speedup vs baseline: 4.3200x; 1.2292x over previous
//
#include <hip/hip_runtime.h>
#include <hip/hip_bf16.h>
#include <cstdint>
#include <cstddef>

#define B_N 4096
#define S_N 64
#define H_N 768
#define L_N 5
#define TEMP_INV (1.0f / 0.07f)
#define BN_EPS 1e-5f

typedef __attribute__((ext_vector_type(8))) short short8;
typedef __attribute__((ext_vector_type(4))) float f32x4;

// ---------- async global->LDS 16B ----------
__device__ __forceinline__ void async_copy16(void* lds, const void* g) {
  __builtin_amdgcn_global_load_lds(
      (const __attribute__((address_space(1))) unsigned int*)g,
      (__attribute__((address_space(3))) unsigned int*)lds, 16, 0, 0);
}

__device__ __forceinline__ unsigned short bf16b(float x) {
  __hip_bfloat16 h = __float2bfloat16(x);
  return *reinterpret_cast<unsigned short*>(&h);
}
__device__ __forceinline__ void store_bf16x4(void* p, float4 v) {
  ushort4 o = make_ushort4(bf16b(v.x), bf16b(v.y), bf16b(v.z), bf16b(v.w));
  *reinterpret_cast<ushort4*>(p) = o;
}

// ---------- block reduction (256 threads = 4 waves) ----------
__device__ inline float block_reduce_sum256(float v, float* sbuf) {
#pragma unroll
  for (int off = 32; off > 0; off >>= 1) v += __shfl_down(v, off, 64);
  int lane = threadIdx.x & 63;
  int wid = threadIdx.x >> 6;
  __syncthreads();
  if (lane == 0) sbuf[wid] = v;
  __syncthreads();
  float r = 0.f;
  if (threadIdx.x == 0) r = sbuf[0] + sbuf[1] + sbuf[2] + sbuf[3];
  return r;  // valid on thread 0 only
}

// ---------- K1: fused extract + row norms + column stats (single seq pass) ----------
// 256 blocks x 16 rows. Threads 0..191 each own 4 columns (float4).
__global__ __launch_bounds__(256) void extract_kernel(
    const float* __restrict__ seq, __hip_bfloat16* __restrict__ zb,
    __hip_bfloat16* __restrict__ tb, float* __restrict__ zn_inv,
    float* __restrict__ thn_inv, float* __restrict__ sum_z,
    float* __restrict__ ssq_z, float* __restrict__ sum_t,
    float* __restrict__ ssq_t) {
  __shared__ float pr[16][6][3];  // row, {z,l0..l4}, wave
  int t = threadIdx.x;
  int wv = t >> 6, ln = t & 63;
  bool act = t < 192;
  int c4 = t * 4;
  int b0 = blockIdx.x * 16;
  float zs[4] = {}, zq[4] = {}, ts4[4] = {}, tq4[4] = {};
  for (int r = 0; r < 16; ++r) {
    int b = b0 + r;
    const float* base = seq + (size_t)b * (S_N * H_N);
    float pv[6] = {0.f, 0.f, 0.f, 0.f, 0.f, 0.f};
    if (act) {
      float4 z4 = *(const float4*)(base + c4);
      store_bf16x4(zb + (size_t)b * H_N + c4, z4);
      pv[0] = z4.x * z4.x + z4.y * z4.y + z4.z * z4.z + z4.w * z4.w;
      zs[0] += z4.x; zs[1] += z4.y; zs[2] += z4.z; zs[3] += z4.w;
      zq[0] += z4.x * z4.x; zq[1] += z4.y * z4.y;
      zq[2] += z4.z * z4.z; zq[3] += z4.w * z4.w;
#pragma unroll
      for (int l = 0; l < L_N; ++l) {
        float4 v4;
        if (l == 0) {
          float4 a4 = *(const float4*)(base + H_N + c4);
          float4 b4 = *(const float4*)(base + 2 * H_N + c4);
          v4 = make_float4(0.5f * (a4.x + b4.x), 0.5f * (a4.y + b4.y),
                           0.5f * (a4.z + b4.z), 0.5f * (a4.w + b4.w));
        } else {
          v4 = *(const float4*)(base + (size_t)(l + 2) * H_N + c4);
        }
        store_bf16x4(tb + ((size_t)b * L_N + l) * H_N + c4, v4);
        pv[1 + l] = v4.x * v4.x + v4.y * v4.y + v4.z * v4.z + v4.w * v4.w;
        ts4[0] += v4.x; ts4[1] += v4.y; ts4[2] += v4.z; ts4[3] += v4.w;
        tq4[0] += v4.x * v4.x; tq4[1] += v4.y * v4.y;
        tq4[2] += v4.z * v4.z; tq4[3] += v4.w * v4.w;
      }
    }
#pragma unroll
    for (int v = 0; v < 6; ++v) {
      float x = pv[v];
#pragma unroll
      for (int off = 32; off > 0; off >>= 1) x += __shfl_down(x, off, 64);
      if (ln == 0 && wv < 3) pr[r][v][wv] = x;
    }
  }
  __syncthreads();
  if (t < 96) {
    int r = t / 6, v = t - r * 6;
    float s = pr[r][v][0] + pr[r][v][1] + pr[r][v][2];
    float inv = 1.f / fmaxf(sqrtf(s), 1e-12f);
    int b = b0 + r;
    if (v == 0) zn_inv[b] = inv;
    else thn_inv[b * L_N + (v - 1)] = inv;
  }
  if (act) {
#pragma unroll
    for (int j = 0; j < 4; ++j) {
      atomicAdd(&sum_z[c4 + j], zs[j]);
      atomicAdd(&ssq_z[c4 + j], zq[j]);
      atomicAdd(&sum_t[c4 + j], ts4[j]);
      atomicAdd(&ssq_t[c4 + j], tq4[j]);
    }
  }
}

// ---------- label histogram ----------
__global__ void count_kernel(const int* __restrict__ labels, int* __restrict__ cnt) {
  int i = blockIdx.x * 256 + threadIdx.x;
  if (i < B_N) atomicAdd(&cnt[labels[i]], 1);
}

// ---------- K3: bn affine coefficients ----------
__global__ void finalize_kernel(
    const float* __restrict__ sum_z, const float* __restrict__ ssq_z,
    const float* __restrict__ sum_t, const float* __restrict__ ssq_t,
    const float* __restrict__ g_z, const float* __restrict__ b_z,
    const float* __restrict__ g_t, const float* __restrict__ b_t,
    float* __restrict__ sz_s, float* __restrict__ sz_t,
    float* __restrict__ st_s, float* __restrict__ st_t) {
  int h = blockIdx.x * 256 + threadIdx.x;
  if (h >= H_N) return;
  {
    float m = sum_z[h] * (1.f / B_N);
    float v = ssq_z[h] * (1.f / B_N) - m * m;
    float s = g_z[h] * rsqrtf(v + BN_EPS);
    sz_s[h] = s;
    sz_t[h] = b_z[h] - m * s;
  }
  {
    float m = sum_t[h] * (1.f / (B_N * L_N));
    float v = ssq_t[h] * (1.f / (B_N * L_N)) - m * m;
    float s = g_t[h] * rsqrtf(v + BN_EPS);
    st_s[h] = s;
    st_t[h] = b_t[h] - m * s;
  }
}

// ---------- K3b: fold BN scale into cls_W (bf16) + folded bias ----------
// Wcb[n,k] = bf16(cls_W[n,k]*sz_s[k]);  cprime[n] = sum_k sz_t[k]*cls_W[n,k] + cls_b[n]
__global__ __launch_bounds__(256) void prep_cls_kernel(
    const float* __restrict__ W, const float* __restrict__ szs,
    const float* __restrict__ szt, const float* __restrict__ bias,
    __hip_bfloat16* __restrict__ Wb, float* __restrict__ cprime) {
  __shared__ float sbuf[4];
  int n = blockIdx.x;
  int t = threadIdx.x;
  float dot = 0.f;
  if (t < 192) {
    int c4 = t * 4;
    const float* row = W + (size_t)n * H_N;
    float4 w4 = *(const float4*)(row + c4);
    float4 s4 = *(const float4*)(szs + c4);
    float4 t4 = *(const float4*)(szt + c4);
    store_bf16x4(Wb + (size_t)n * H_N + c4,
                 make_float4(w4.x * s4.x, w4.y * s4.y, w4.z * s4.z, w4.w * s4.w));
    dot = w4.x * t4.x + w4.y * t4.y + w4.z * t4.z + w4.w * t4.w;
  }
  float s = block_reduce_sum256(dot, sbuf);
  if (t == 0) cprime[n] = s + bias[n];
}

// ---------- K3c: WlT[k][n] = bf16(label_W[n][k]) (tiled transpose) ----------
__global__ __launch_bounds__(256) void transpose_wl_kernel(
    const float* __restrict__ Wl, __hip_bfloat16* __restrict__ WlT) {
  __shared__ float tile[32][33];
  int t = threadIdx.x;
  int tx = t & 31, ty0 = t >> 5;  // 8 rows per pass
  int n0 = blockIdx.x * 32, k0 = blockIdx.y * 32;
#pragma unroll
  for (int p = 0; p < 4; ++p)
    tile[ty0 + p * 8][tx] = Wl[(size_t)(n0 + ty0 + p * 8) * H_N + k0 + tx];
  __syncthreads();
#pragma unroll
  for (int p = 0; p < 4; ++p) {
    unsigned short us = bf16b(tile[tx][ty0 + p * 8]);
    *((unsigned short*)WlT + (size_t)(k0 + ty0 + p * 8) * H_N + n0 + tx) = us;
  }
}

// ---------- K4/K5: 128x128 bf16 MFMA GEMM template (B^T layout, K=768) ----------
template <bool WRITE_BF16, bool HAS_BIAS>
__global__ __launch_bounds__(256) void gemm128_kernel(
    const __hip_bfloat16* __restrict__ A, const __hip_bfloat16* __restrict__ Bm,
    const float* __restrict__ bias, float* __restrict__ outF,
    __hip_bfloat16* __restrict__ outB) {
  __shared__ __align__(16) __hip_bfloat16 Asm[128 * 32];
  __shared__ __align__(16) __hip_bfloat16 Bsm[128 * 32];
  int tid = threadIdx.x, lane = tid & 63, wid = tid >> 6;
  int wr = wid >> 1, wc = wid & 1;
  int i0 = blockIdx.x * 128, n0 = blockIdx.y * 128;
  int llo = lane & 15, lhi = lane >> 4;
  f32x4 acc[4][4] = {};
  for (int k0 = 0; k0 < H_N; k0 += 32) {
#pragma unroll
    for (int r = 0; r < 2; ++r) {
      int s = r * 256 + wid * 64 + lane;
      int row = s >> 2, kc = (s & 3) * 8;
      size_t go = (size_t)row * H_N + k0 + kc;
      async_copy16((char*)Asm + (size_t)(r * 256 + wid * 64) * 16,
                   A + (size_t)i0 * H_N + go);
      async_copy16((char*)Bsm + (size_t)(r * 256 + wid * 64) * 16,
                   Bm + (size_t)n0 * H_N + go);
    }
    __syncthreads();
    short8 a[4], b[4];
#pragma unroll
    for (int m = 0; m < 4; ++m)
      a[m] = *(const short8*)((const char*)Asm +
                              ((wr * 64 + m * 16 + llo) * 32 + lhi * 8) * 2);
#pragma unroll
    for (int n = 0; n < 4; ++n)
      b[n] = *(const short8*)((const char*)Bsm +
                              ((wc * 64 + n * 16 + llo) * 32 + lhi * 8) * 2);
#pragma unroll
    for (int m = 0; m < 4; ++m)
#pragma unroll
      for (int n = 0; n < 4; ++n)
        acc[m][n] =
            __builtin_amdgcn_mfma_f32_16x16x32_bf16(a[m], b[n], acc[m][n], 0, 0, 0);
    __syncthreads();
  }
#pragma unroll
  for (int n = 0; n < 4; ++n) {
    int col = n0 + wc * 64 + n * 16 + llo;
    float bv = HAS_BIAS ? bias[col] : 0.f;
#pragma unroll
    for (int m = 0; m < 4; ++m) {
#pragma unroll
      for (int r = 0; r < 4; ++r) {
        int row = i0 + wr * 64 + m * 16 + lhi * 4 + r;
        float val = acc[m][n][r] + bv;
        outF[(size_t)row * H_N + col] = val;
        if (WRITE_BF16)
          outB[(size_t)row * H_N + col] = __float2bfloat16(val);
      }
    }
  }
}

// ---------- K6: logits[b,l] = theta[b,l]·(st_s⊙u[b]) + st_t·u[b] + label_b·zp[b] ----------
__global__ __launch_bounds__(256) void logits_kernel(
    const float* __restrict__ seq, const float* __restrict__ u,
    const float* __restrict__ zp, const float* __restrict__ st_s,
    const float* __restrict__ st_t, const float* __restrict__ label_b,
    float* __restrict__ out) {
  __shared__ float sbuf[4];
  int b = blockIdx.x;
  int t = threadIdx.x;
  bool act = t < 192;
  int c4 = t * 4;
  float4 w4 = make_float4(0.f, 0.f, 0.f, 0.f);
  float apart = 0.f;
  if (act) {
    float4 u4 = *(const float4*)(u + (size_t)b * H_N + c4);
    float4 zp4 = *(const float4*)(zp + (size_t)b * H_N + c4);
    float4 ss4 = *(const float4*)(st_s + c4);
    float4 tt4 = *(const float4*)(st_t + c4);
    float4 lb4 = *(const float4*)(label_b + c4);
    w4 = make_float4(u4.x * ss4.x, u4.y * ss4.y, u4.z * ss4.z, u4.w * ss4.w);
    apart = u4.x * tt4.x + u4.y * tt4.y + u4.z * tt4.z + u4.w * tt4.w +
            zp4.x * lb4.x + zp4.y * lb4.y + zp4.z * lb4.z + zp4.w * lb4.w;
  }
  float alpha = block_reduce_sum256(apart, sbuf);  // valid on t0
  const float* base = seq + (size_t)b * (S_N * H_N);
#pragma unroll
  for (int l = 0; l < L_N; ++l) {
    float part = 0.f;
    if (act) {
      float4 v4;
      if (l == 0) {
        float4 a4 = *(const float4*)(base + H_N + c4);
        float4 b4 = *(const float4*)(base + 2 * H_N + c4);
        v4 = make_float4(0.5f * (a4.x + b4.x), 0.5f * (a4.y + b4.y),
                         0.5f * (a4.z + b4.z), 0.5f * (a4.w + b4.w));
      } else {
        v4 = *(const float4*)(base + (size_t)(l + 2) * H_N + c4);
      }
      part = v4.x * w4.x + v4.y * w4.y + v4.z * w4.z + v4.w * w4.w;
    }
    float s = block_reduce_sum256(part, sbuf);
    if (t == 0) out[b * L_N + l] = s + alpha;
  }
}

// ---------- K7: bf16 MFMA GEMM S = z @ theta^T, fused exp/mask epilogue ----------
__global__ __launch_bounds__(256) void sgemm_fused_kernel(
    const __hip_bfloat16* __restrict__ zb, const __hip_bfloat16* __restrict__ tb,
    const float* __restrict__ zn_inv, const float* __restrict__ thn_inv,
    const int* __restrict__ labels, float* __restrict__ pos_z,
    float* __restrict__ neg_z, float* __restrict__ pos_t,
    float* __restrict__ neg_t) {
  __shared__ __align__(16) __hip_bfloat16 Asm[128 * 32];
  __shared__ __align__(16) __hip_bfloat16 Bsm[128 * 32];
  __shared__ float rpos[128], rneg[128], cpos[128], cneg[128];
  __shared__ float rnorm[128], cnorm[128];
  __shared__ int rowlab[128], colj[128], coll[128], collab[128];

  int tid = threadIdx.x;
  int lane = tid & 63, wid = tid >> 6;
  int wr = wid >> 1, wc = wid & 1;
  int i0 = blockIdx.x * 128, n0 = blockIdx.y * 128;
  int llo = lane & 15, lhi = lane >> 4;

  f32x4 acc[4][4] = {};

  for (int k0 = 0; k0 < H_N; k0 += 32) {
#pragma unroll
    for (int r = 0; r < 2; ++r) {
      int s = r * 256 + wid * 64 + lane;
      int row = s >> 2, kc = (s & 3) * 8;
      size_t go = (size_t)row * H_N + k0 + kc;
      async_copy16((char*)Asm + (size_t)(r * 256 + wid * 64) * 16,
                   zb + (size_t)i0 * H_N + go);
      async_copy16((char*)Bsm + (size_t)(r * 256 + wid * 64) * 16,
                   tb + (size_t)n0 * H_N + go);
    }
    __syncthreads();
    short8 a[4], b[4];
#pragma unroll
    for (int m = 0; m < 4; ++m)
      a[m] = *(const short8*)((const char*)Asm +
                              ((wr * 64 + m * 16 + llo) * 32 + lhi * 8) * 2);
#pragma unroll
    for (int n = 0; n < 4; ++n)
      b[n] = *(const short8*)((const char*)Bsm +
                              ((wc * 64 + n * 16 + llo) * 32 + lhi * 8) * 2);
#pragma unroll
    for (int m = 0; m < 4; ++m)
#pragma unroll
      for (int n = 0; n < 4; ++n)
        acc[m][n] =
            __builtin_amdgcn_mfma_f32_16x16x32_bf16(a[m], b[n], acc[m][n], 0, 0, 0);
    __syncthreads();
  }

  if (tid < 128) {
    rowlab[tid] = labels[i0 + tid];
    rnorm[tid] = zn_inv[i0 + tid] * TEMP_INV;
    int c = n0 + tid;
    int j = c / 5;
    colj[tid] = j;
    coll[tid] = c - j * 5;
    collab[tid] = labels[j];
    cnorm[tid] = thn_inv[c];
    rpos[tid] = 0.f; rneg[tid] = 0.f; cpos[tid] = 0.f; cneg[tid] = 0.f;
  }
  __syncthreads();

  int cl[4], jg[4], lv[4], lj[4];
  float cs[4];
#pragma unroll
  for (int n = 0; n < 4; ++n) {
    cl[n] = wc * 64 + n * 16 + llo;
    jg[n] = colj[cl[n]];
    lv[n] = coll[cl[n]];
    lj[n] = collab[cl[n]];
    cs[n] = cnorm[cl[n]];
  }
  float cpAcc[4] = {}, cnAcc[4] = {};
#pragma unroll
  for (int m = 0; m < 4; ++m) {
#pragma unroll
    for (int r = 0; r < 4; ++r) {
      int rl = wr * 64 + m * 16 + lhi * 4 + r;
      int ig = i0 + rl;
      int li = rowlab[rl];
      float rscale = rnorm[rl];
      float rp = 0.f, rn = 0.f;
#pragma unroll
      for (int n = 0; n < 4; ++n) {
        float e = __expf(acc[m][n][r] * rscale * cs[n]);
        bool same = (li == lj[n]);
        bool diag = (ig == jg[n]);
        if (same) {
          if (!diag && lv[n] == li) { rp += e; cpAcc[n] += e; }
        } else {
          rn += e;
          if (lv[n] == lj[n]) cnAcc[n] += e;
        }
      }
      if (rp != 0.f) atomicAdd(&rpos[rl], rp);
      if (rn != 0.f) atomicAdd(&rneg[rl], rn);
    }
  }
#pragma unroll
  for (int n = 0; n < 4; ++n) {
    if (cpAcc[n] != 0.f) atomicAdd(&cpos[cl[n]], cpAcc[n]);
    if (cnAcc[n] != 0.f) atomicAdd(&cneg[cl[n]], cnAcc[n]);
  }
  __syncthreads();
  if (tid < 128) {
    float v;
    v = rpos[tid]; if (v != 0.f) atomicAdd(&pos_z[i0 + tid], v);
    v = rneg[tid]; if (v != 0.f) atomicAdd(&neg_z[i0 + tid], v);
    int j = colj[tid];
    v = cpos[tid]; if (v != 0.f) atomicAdd(&pos_t[j], v);
    v = cneg[tid]; if (v != 0.f) atomicAdd(&neg_t[j], v);
  }
}

// ---------- K8: final loss ----------
__global__ __launch_bounds__(256) void loss_kernel(
    const float* __restrict__ pos_z, const float* __restrict__ neg_z,
    const float* __restrict__ pos_t, const float* __restrict__ neg_t,
    const int* __restrict__ labels, const int* __restrict__ cnt,
    float* __restrict__ out_loss) {
  __shared__ float sbuf[4];
  int i = blockIdx.x * 256 + threadIdx.x;
  float term = 0.f;
  int li = labels[i];
  if (cnt[li] > 1) {
    float pz = pos_z[i], nz = neg_z[i];
    float pt = pos_t[i], nt = neg_t[i];
    term = -logf(pz / (pz + nz + 1e-8f)) - logf(pt / (pt + nt + 1e-8f));
  }
  float s = block_reduce_sum256(term, sbuf);
  if (threadIdx.x == 0) atomicAdd(out_loss, s * (1.0f / B_N));
}

// ---------- launch ----------
extern "C" void kernel_launch(void* const* d_in, const int* in_sizes, int n_in,
                              void* d_out, int out_size, void* d_ws, size_t ws_size,
                              hipStream_t stream) {
  const float* seq = (const float*)d_in[0];
  const float* cls_gamma = (const float*)d_in[1];
  const float* cls_beta = (const float*)d_in[2];
  const float* cls_W = (const float*)d_in[3];
  const float* cls_b = (const float*)d_in[4];
  const float* label_gamma = (const float*)d_in[5];
  const float* label_beta = (const float*)d_in[6];
  const float* label_W = (const float*)d_in[7];
  const float* label_b = (const float*)d_in[8];
  const int* labels = (const int*)d_in[9];
  float* out = (float*)d_out;
  float* ws = (float*)d_ws;

  constexpr size_t OFF_SUMZ = 0;
  constexpr size_t OFF_SSQZ = 768;
  constexpr size_t OFF_SUMT = 1536;
  constexpr size_t OFF_SSQT = 2304;
  constexpr size_t OFF_POSZ = 3072;
  constexpr size_t OFF_NEGZ = 7168;
  constexpr size_t OFF_POST = 11264;
  constexpr size_t OFF_NEGT = 15360;
  constexpr size_t OFF_CNT = 19456;  // 8 ints
  constexpr size_t ZERO_FLOATS = 19464;
  constexpr size_t OFF_SZS = 19464;
  constexpr size_t OFF_SZT = 20232;
  constexpr size_t OFF_STS = 21000;
  constexpr size_t OFF_STT = 21768;
  constexpr size_t OFF_ZNI = 22536;   // 4096
  constexpr size_t OFF_TNI = 26632;   // 20480
  constexpr size_t OFF_CPRIME = 47112;  // 768
  constexpr size_t OFF_ZP = 47880;      // 4096*768 fp32
  constexpr size_t OFF_U = OFF_ZP + (size_t)B_N * H_N;
  constexpr size_t F32_END = OFF_U + (size_t)B_N * H_N;
  constexpr size_t BYTE_ZB = F32_END * sizeof(float);           // bf16 z
  constexpr size_t BYTE_TB = BYTE_ZB + (size_t)B_N * H_N * 2;   // bf16 theta
  constexpr size_t BYTE_ZPB = BYTE_TB + (size_t)B_N * L_N * H_N * 2;  // bf16 zp
  constexpr size_t BYTE_WCB = BYTE_ZPB + (size_t)B_N * H_N * 2;       // bf16 Wc'
  constexpr size_t BYTE_WLT = BYTE_WCB + (size_t)H_N * H_N * 2;       // bf16 Wl^T
  constexpr size_t TOTAL_BYTES = BYTE_WLT + (size_t)H_N * H_N * 2;
  if (ws_size < TOTAL_BYTES) return;

  __hip_bfloat16* zb = (__hip_bfloat16*)((char*)d_ws + BYTE_ZB);
  __hip_bfloat16* tb = (__hip_bfloat16*)((char*)d_ws + BYTE_TB);
  __hip_bfloat16* zpb = (__hip_bfloat16*)((char*)d_ws + BYTE_ZPB);
  __hip_bfloat16* wcb = (__hip_bfloat16*)((char*)d_ws + BYTE_WCB);
  __hip_bfloat16* wlt = (__hip_bfloat16*)((char*)d_ws + BYTE_WLT);

  hipMemsetAsync(d_ws, 0, ZERO_FLOATS * sizeof(float), stream);
  hipMemsetAsync((char*)d_out + (size_t)B_N * L_N * sizeof(float), 0, sizeof(float),
                 stream);

  extract_kernel<<<256, 256, 0, stream>>>(seq, zb, tb, ws + OFF_ZNI, ws + OFF_TNI,
                                          ws + OFF_SUMZ, ws + OFF_SSQZ,
                                          ws + OFF_SUMT, ws + OFF_SSQT);
  count_kernel<<<16, 256, 0, stream>>>(labels, (int*)(ws + OFF_CNT));
  finalize_kernel<<<3, 256, 0, stream>>>(
      ws + OFF_SUMZ, ws + OFF_SSQZ, ws + OFF_SUMT, ws + OFF_SSQT, cls_gamma,
      cls_beta, label_gamma, label_beta, ws + OFF_SZS, ws + OFF_SZT, ws + OFF_STS,
      ws + OFF_STT);
  prep_cls_kernel<<<H_N, 256, 0, stream>>>(cls_W, ws + OFF_SZS, ws + OFF_SZT, cls_b,
                                           wcb, ws + OFF_CPRIME);
  transpose_wl_kernel<<<dim3(24, 24), 256, 0, stream>>>(label_W, wlt);
  gemm128_kernel<true, true><<<dim3(32, 6), 256, 0, stream>>>(
      zb, wcb, ws + OFF_CPRIME, ws + OFF_ZP, zpb);
  gemm128_kernel<false, false><<<dim3(32, 6), 256, 0, stream>>>(
      zpb, wlt, nullptr, ws + OFF_U, nullptr);
  logits_kernel<<<B_N, 256, 0, stream>>>(seq, ws + OFF_U, ws + OFF_ZP, ws + OFF_STS,
                                         ws + OFF_STT, label_b, out);
  sgemm_fused_kernel<<<dim3(32, 160), 256, 0, stream>>>(
      zb, tb, ws + OFF_ZNI, ws + OFF_TNI, labels, ws + OFF_POSZ, ws + OFF_NEGZ,
      ws + OFF_POST, ws + OFF_NEGT);
  loss_kernel<<<16, 256, 0, stream>>>(ws + OFF_POSZ, ws + OFF_NEGZ, ws + OFF_POST,
                                      ws + OFF_NEGT, labels,
                                      (const int*)(ws + OFF_CNT),
                                      out + (size_t)B_N * L_N);
}

// Round 4
// 469.108 us; speedup vs baseline: 4.6281x; 1.0713x over previous
//
#include <hip/hip_runtime.h>
#include <hip/hip_bf16.h>
#include <cstdint>
#include <cstddef>

#define B_N 4096
#define S_N 64
#define H_N 768
#define L_N 5
#define TEMP_INV (1.0f / 0.07f)
#define BN_EPS 1e-5f

typedef __attribute__((ext_vector_type(8))) short short8;
typedef __attribute__((ext_vector_type(4))) float f32x4;

// ---------- async global->LDS 16B ----------
__device__ __forceinline__ void async_copy16(void* lds, const void* g) {
  __builtin_amdgcn_global_load_lds(
      (const __attribute__((address_space(1))) unsigned int*)g,
      (__attribute__((address_space(3))) unsigned int*)lds, 16, 0, 0);
}

__device__ __forceinline__ unsigned short bf16b(float x) {
  __hip_bfloat16 h = __float2bfloat16(x);
  return *reinterpret_cast<unsigned short*>(&h);
}
__device__ __forceinline__ void store_bf16x4(void* p, float4 v) {
  ushort4 o = make_ushort4(bf16b(v.x), bf16b(v.y), bf16b(v.z), bf16b(v.w));
  *reinterpret_cast<ushort4*>(p) = o;
}

// ---------- block reduction (256 threads = 4 waves) ----------
__device__ inline float block_reduce_sum256(float v, float* sbuf) {
#pragma unroll
  for (int off = 32; off > 0; off >>= 1) v += __shfl_down(v, off, 64);
  int lane = threadIdx.x & 63;
  int wid = threadIdx.x >> 6;
  __syncthreads();
  if (lane == 0) sbuf[wid] = v;
  __syncthreads();
  float r = 0.f;
  if (threadIdx.x == 0) r = sbuf[0] + sbuf[1] + sbuf[2] + sbuf[3];
  return r;  // valid on thread 0 only
}

// ---------- K1: fused extract + row norms + column stats (single seq pass) ----------
__global__ __launch_bounds__(256) void extract_kernel(
    const float* __restrict__ seq, __hip_bfloat16* __restrict__ zb,
    __hip_bfloat16* __restrict__ tb, float* __restrict__ zn_inv,
    float* __restrict__ thn_inv, float* __restrict__ sum_z,
    float* __restrict__ ssq_z, float* __restrict__ sum_t,
    float* __restrict__ ssq_t) {
  __shared__ float pr[16][6][3];  // row, {z,l0..l4}, wave
  int t = threadIdx.x;
  int wv = t >> 6, ln = t & 63;
  bool act = t < 192;
  int c4 = t * 4;
  int b0 = blockIdx.x * 16;
  float zs[4] = {}, zq[4] = {}, ts4[4] = {}, tq4[4] = {};
  for (int r = 0; r < 16; ++r) {
    int b = b0 + r;
    const float* base = seq + (size_t)b * (S_N * H_N);
    float pv[6] = {0.f, 0.f, 0.f, 0.f, 0.f, 0.f};
    if (act) {
      float4 z4 = *(const float4*)(base + c4);
      store_bf16x4(zb + (size_t)b * H_N + c4, z4);
      pv[0] = z4.x * z4.x + z4.y * z4.y + z4.z * z4.z + z4.w * z4.w;
      zs[0] += z4.x; zs[1] += z4.y; zs[2] += z4.z; zs[3] += z4.w;
      zq[0] += z4.x * z4.x; zq[1] += z4.y * z4.y;
      zq[2] += z4.z * z4.z; zq[3] += z4.w * z4.w;
#pragma unroll
      for (int l = 0; l < L_N; ++l) {
        float4 v4;
        if (l == 0) {
          float4 a4 = *(const float4*)(base + H_N + c4);
          float4 b4 = *(const float4*)(base + 2 * H_N + c4);
          v4 = make_float4(0.5f * (a4.x + b4.x), 0.5f * (a4.y + b4.y),
                           0.5f * (a4.z + b4.z), 0.5f * (a4.w + b4.w));
        } else {
          v4 = *(const float4*)(base + (size_t)(l + 2) * H_N + c4);
        }
        store_bf16x4(tb + ((size_t)b * L_N + l) * H_N + c4, v4);
        pv[1 + l] = v4.x * v4.x + v4.y * v4.y + v4.z * v4.z + v4.w * v4.w;
        ts4[0] += v4.x; ts4[1] += v4.y; ts4[2] += v4.z; ts4[3] += v4.w;
        tq4[0] += v4.x * v4.x; tq4[1] += v4.y * v4.y;
        tq4[2] += v4.z * v4.z; tq4[3] += v4.w * v4.w;
      }
    }
#pragma unroll
    for (int v = 0; v < 6; ++v) {
      float x = pv[v];
#pragma unroll
      for (int off = 32; off > 0; off >>= 1) x += __shfl_down(x, off, 64);
      if (ln == 0 && wv < 3) pr[r][v][wv] = x;
    }
  }
  __syncthreads();
  if (t < 96) {
    int r = t / 6, v = t - r * 6;
    float s = pr[r][v][0] + pr[r][v][1] + pr[r][v][2];
    float inv = 1.f / fmaxf(sqrtf(s), 1e-12f);
    int b = b0 + r;
    if (v == 0) zn_inv[b] = inv;
    else thn_inv[b * L_N + (v - 1)] = inv;
  }
  if (act) {
#pragma unroll
    for (int j = 0; j < 4; ++j) {
      atomicAdd(&sum_z[c4 + j], zs[j]);
      atomicAdd(&ssq_z[c4 + j], zq[j]);
      atomicAdd(&sum_t[c4 + j], ts4[j]);
      atomicAdd(&ssq_t[c4 + j], tq4[j]);
    }
  }
}

// ---------- label histogram ----------
__global__ void count_kernel(const int* __restrict__ labels, int* __restrict__ cnt) {
  int i = blockIdx.x * 256 + threadIdx.x;
  if (i < B_N) atomicAdd(&cnt[labels[i]], 1);
}

// ---------- K3: bn affine coefficients ----------
__global__ void finalize_kernel(
    const float* __restrict__ sum_z, const float* __restrict__ ssq_z,
    const float* __restrict__ sum_t, const float* __restrict__ ssq_t,
    const float* __restrict__ g_z, const float* __restrict__ b_z,
    const float* __restrict__ g_t, const float* __restrict__ b_t,
    float* __restrict__ sz_s, float* __restrict__ sz_t,
    float* __restrict__ st_s, float* __restrict__ st_t) {
  int h = blockIdx.x * 256 + threadIdx.x;
  if (h >= H_N) return;
  {
    float m = sum_z[h] * (1.f / B_N);
    float v = ssq_z[h] * (1.f / B_N) - m * m;
    float s = g_z[h] * rsqrtf(v + BN_EPS);
    sz_s[h] = s;
    sz_t[h] = b_z[h] - m * s;
  }
  {
    float m = sum_t[h] * (1.f / (B_N * L_N));
    float v = ssq_t[h] * (1.f / (B_N * L_N)) - m * m;
    float s = g_t[h] * rsqrtf(v + BN_EPS);
    st_s[h] = s;
    st_t[h] = b_t[h] - m * s;
  }
}

// ---------- K3b: fold BN scale into cls_W (bf16) + folded bias ----------
__global__ __launch_bounds__(256) void prep_cls_kernel(
    const float* __restrict__ W, const float* __restrict__ szs,
    const float* __restrict__ szt, const float* __restrict__ bias,
    __hip_bfloat16* __restrict__ Wb, float* __restrict__ cprime) {
  __shared__ float sbuf[4];
  int n = blockIdx.x;
  int t = threadIdx.x;
  float dot = 0.f;
  if (t < 192) {
    int c4 = t * 4;
    const float* row = W + (size_t)n * H_N;
    float4 w4 = *(const float4*)(row + c4);
    float4 s4 = *(const float4*)(szs + c4);
    float4 t4 = *(const float4*)(szt + c4);
    store_bf16x4(Wb + (size_t)n * H_N + c4,
                 make_float4(w4.x * s4.x, w4.y * s4.y, w4.z * s4.z, w4.w * s4.w));
    dot = w4.x * t4.x + w4.y * t4.y + w4.z * t4.z + w4.w * t4.w;
  }
  float s = block_reduce_sum256(dot, sbuf);
  if (t == 0) cprime[n] = s + bias[n];
}

// ---------- K3c: WlT[k][n] = bf16(label_W[n][k]) ----------
__global__ __launch_bounds__(256) void transpose_wl_kernel(
    const float* __restrict__ Wl, __hip_bfloat16* __restrict__ WlT) {
  __shared__ float tile[32][33];
  int t = threadIdx.x;
  int tx = t & 31, ty0 = t >> 5;
  int n0 = blockIdx.x * 32, k0 = blockIdx.y * 32;
#pragma unroll
  for (int p = 0; p < 4; ++p)
    tile[ty0 + p * 8][tx] = Wl[(size_t)(n0 + ty0 + p * 8) * H_N + k0 + tx];
  __syncthreads();
#pragma unroll
  for (int p = 0; p < 4; ++p) {
    unsigned short us = bf16b(tile[tx][ty0 + p * 8]);
    *((unsigned short*)WlT + (size_t)(k0 + ty0 + p * 8) * H_N + n0 + tx) = us;
  }
}

// ---------- K4/K5: 128x128 bf16 MFMA GEMM template ----------
template <bool WRITE_BF16, bool HAS_BIAS>
__global__ __launch_bounds__(256) void gemm128_kernel(
    const __hip_bfloat16* __restrict__ A, const __hip_bfloat16* __restrict__ Bm,
    const float* __restrict__ bias, float* __restrict__ outF,
    __hip_bfloat16* __restrict__ outB) {
  __shared__ __align__(16) __hip_bfloat16 Asm[128 * 32];
  __shared__ __align__(16) __hip_bfloat16 Bsm[128 * 32];
  int tid = threadIdx.x, lane = tid & 63, wid = tid >> 6;
  int wr = wid >> 1, wc = wid & 1;
  int i0 = blockIdx.x * 128, n0 = blockIdx.y * 128;
  int llo = lane & 15, lhi = lane >> 4;
  f32x4 acc[4][4] = {};
  for (int k0 = 0; k0 < H_N; k0 += 32) {
#pragma unroll
    for (int r = 0; r < 2; ++r) {
      int s = r * 256 + wid * 64 + lane;
      int row = s >> 2, kc = (s & 3) * 8;
      size_t go = (size_t)row * H_N + k0 + kc;
      async_copy16((char*)Asm + (size_t)(r * 256 + wid * 64) * 16,
                   A + (size_t)i0 * H_N + go);
      async_copy16((char*)Bsm + (size_t)(r * 256 + wid * 64) * 16,
                   Bm + (size_t)n0 * H_N + go);
    }
    __syncthreads();
    short8 a[4], b[4];
#pragma unroll
    for (int m = 0; m < 4; ++m)
      a[m] = *(const short8*)((const char*)Asm +
                              ((wr * 64 + m * 16 + llo) * 32 + lhi * 8) * 2);
#pragma unroll
    for (int n = 0; n < 4; ++n)
      b[n] = *(const short8*)((const char*)Bsm +
                              ((wc * 64 + n * 16 + llo) * 32 + lhi * 8) * 2);
#pragma unroll
    for (int m = 0; m < 4; ++m)
#pragma unroll
      for (int n = 0; n < 4; ++n)
        acc[m][n] =
            __builtin_amdgcn_mfma_f32_16x16x32_bf16(a[m], b[n], acc[m][n], 0, 0, 0);
    __syncthreads();
  }
#pragma unroll
  for (int n = 0; n < 4; ++n) {
    int col = n0 + wc * 64 + n * 16 + llo;
    float bv = HAS_BIAS ? bias[col] : 0.f;
#pragma unroll
    for (int m = 0; m < 4; ++m) {
#pragma unroll
      for (int r = 0; r < 4; ++r) {
        int row = i0 + wr * 64 + m * 16 + lhi * 4 + r;
        float val = acc[m][n][r] + bv;
        outF[(size_t)row * H_N + col] = val;
        if (WRITE_BF16)
          outB[(size_t)row * H_N + col] = __float2bfloat16(val);
      }
    }
  }
}

// ---------- K6: logits ----------
__global__ __launch_bounds__(256) void logits_kernel(
    const float* __restrict__ seq, const float* __restrict__ u,
    const float* __restrict__ zp, const float* __restrict__ st_s,
    const float* __restrict__ st_t, const float* __restrict__ label_b,
    float* __restrict__ out) {
  __shared__ float sbuf[4];
  int b = blockIdx.x;
  int t = threadIdx.x;
  bool act = t < 192;
  int c4 = t * 4;
  float4 w4 = make_float4(0.f, 0.f, 0.f, 0.f);
  float apart = 0.f;
  if (act) {
    float4 u4 = *(const float4*)(u + (size_t)b * H_N + c4);
    float4 zp4 = *(const float4*)(zp + (size_t)b * H_N + c4);
    float4 ss4 = *(const float4*)(st_s + c4);
    float4 tt4 = *(const float4*)(st_t + c4);
    float4 lb4 = *(const float4*)(label_b + c4);
    w4 = make_float4(u4.x * ss4.x, u4.y * ss4.y, u4.z * ss4.z, u4.w * ss4.w);
    apart = u4.x * tt4.x + u4.y * tt4.y + u4.z * tt4.z + u4.w * tt4.w +
            zp4.x * lb4.x + zp4.y * lb4.y + zp4.z * lb4.z + zp4.w * lb4.w;
  }
  float alpha = block_reduce_sum256(apart, sbuf);
  const float* base = seq + (size_t)b * (S_N * H_N);
#pragma unroll
  for (int l = 0; l < L_N; ++l) {
    float part = 0.f;
    if (act) {
      float4 v4;
      if (l == 0) {
        float4 a4 = *(const float4*)(base + H_N + c4);
        float4 b4 = *(const float4*)(base + 2 * H_N + c4);
        v4 = make_float4(0.5f * (a4.x + b4.x), 0.5f * (a4.y + b4.y),
                         0.5f * (a4.z + b4.z), 0.5f * (a4.w + b4.w));
      } else {
        v4 = *(const float4*)(base + (size_t)(l + 2) * H_N + c4);
      }
      part = v4.x * w4.x + v4.y * w4.y + v4.z * w4.z + v4.w * w4.w;
    }
    float s = block_reduce_sum256(part, sbuf);
    if (t == 0) out[b * L_N + l] = s + alpha;
  }
}

// ---------- K7: 256x256-tile deep-pipelined bf16 MFMA GEMM + fused epilogue ----------
// 8 waves (2M x 4N), BK=64, double-buffered LDS (2 x 64KB), counted vmcnt(8),
// XOR-swizzled LDS (slot ^= row&7 at 16B granularity; inverse applied on the
// per-lane GLOBAL source of global_load_lds — rule #21 both-sides-or-neither).
#define NT_K 12  // 768 / 64
__global__ __launch_bounds__(512, 1) void sgemm_fused_kernel(
    const __hip_bfloat16* __restrict__ zb, const __hip_bfloat16* __restrict__ tb,
    const float* __restrict__ zn_inv, const float* __restrict__ thn_inv,
    const int* __restrict__ labels, float* __restrict__ pos_z,
    float* __restrict__ neg_z, float* __restrict__ pos_t,
    float* __restrict__ neg_t) {
  __shared__ __align__(128) char ldsbuf[2][65536];  // per buf: A 32KB | B 32KB

  const int tid = threadIdx.x;
  const int lane = tid & 63, wid = tid >> 6;
  const int llo = lane & 15, lhi = lane >> 4;
  const int wrbase = (wid >> 2) * 128;  // 2 wave-rows
  const int wcbase = (wid & 3) * 64;    // 4 wave-cols
  const int i0 = blockIdx.x * 256, n0 = blockIdx.y * 256;
  const int wvb = wid << 10;  // wave slot base bytes: (wid*64)*16

  f32x4 acc[8][4] = {};

  // stage K-tile kt into buffer c (8 global_load_lds per thread: 4 A + 4 B)
  auto stage = [&](int c, int kt) {
    char* dA = &ldsbuf[c][0];
    char* dB = &ldsbuf[c][32768];
#pragma unroll
    for (int w = 0; w < 4; ++w) {
      int s = w * 512 + tid;
      int row = s >> 3;                  // 8 x 16B slots per 128B row
      int lq = (s & 7) ^ (row & 7);      // inverse swizzle on global source
      int kofs = kt * 64 + lq * 8;
      async_copy16(dA + w * 8192 + wvb, zb + (size_t)(i0 + row) * H_N + kofs);
      async_copy16(dB + w * 8192 + wvb, tb + (size_t)(n0 + row) * H_N + kofs);
    }
  };

  // prologue: tiles 0,1 in flight; wait tile 0 (8 newest outstanding = tile 1)
  stage(0, 0);
  stage(1, 1);
  asm volatile("s_waitcnt vmcnt(8)" ::: "memory");
  __builtin_amdgcn_s_barrier();

  for (int t = 0; t < NT_K; ++t) {
    const char* ldsA = &ldsbuf[t & 1][0];
    const char* ldsB = &ldsbuf[t & 1][32768];
#pragma unroll
    for (int ks = 0; ks < 2; ++ks) {
      short8 a[8], b[4];
      int slot = ((ks * 4 + lhi) ^ (llo & 7)) * 16;  // swizzled read
#pragma unroll
      for (int mi = 0; mi < 8; ++mi) {
        int row = wrbase + mi * 16 + llo;
        a[mi] = *(const short8*)(ldsA + row * 128 + slot);
      }
#pragma unroll
      for (int ni = 0; ni < 4; ++ni) {
        int col = wcbase + ni * 16 + llo;
        b[ni] = *(const short8*)(ldsB + col * 128 + slot);
      }
      __builtin_amdgcn_s_setprio(1);
#pragma unroll
      for (int mi = 0; mi < 8; ++mi)
#pragma unroll
        for (int ni = 0; ni < 4; ++ni)
          acc[mi][ni] = __builtin_amdgcn_mfma_f32_16x16x32_bf16(a[mi], b[ni],
                                                                acc[mi][ni], 0, 0, 0);
      __builtin_amdgcn_s_setprio(0);
    }
    // all this wave's ds_reads retired (MFMA consumed them); make it explicit
    asm volatile("s_waitcnt lgkmcnt(0)" ::: "memory");
    __builtin_amdgcn_s_barrier();  // every wave done READING buf[t&1]
    if (t < NT_K - 2) {
      stage(t & 1, t + 2);  // overwrite freed buffer
      // outstanding: 8 (tile t+1) + 8 (tile t+2) -> wait until t+1 retired
      asm volatile("s_waitcnt vmcnt(8)" ::: "memory");
    } else {
      asm volatile("s_waitcnt vmcnt(0)" ::: "memory");  // tail drain
    }
    __builtin_amdgcn_s_barrier();  // buf[(t+1)&1] visible to all waves
  }
  __syncthreads();  // full fence before overlaying epilogue arrays onto ldsbuf

  // ---- fused epilogue: exp + masks + row/col reductions (LDS overlay) ----
  float* rpos = (float*)&ldsbuf[0][0];
  float* rneg = rpos + 256;
  float* cpos = rneg + 256;
  float* cneg = cpos + 256;
  float* rnorm = cneg + 256;
  float* cnorm = rnorm + 256;
  int* rowlab = (int*)(cnorm + 256);
  int* colj = rowlab + 256;
  int* coll = colj + 256;
  int* collab = coll + 256;

  if (tid < 256) {
    rowlab[tid] = labels[i0 + tid];
    rnorm[tid] = zn_inv[i0 + tid] * TEMP_INV;
    int c = n0 + tid;
    int j = c / 5;
    colj[tid] = j;
    coll[tid] = c - j * 5;
    collab[tid] = labels[j];
    cnorm[tid] = thn_inv[c];
    rpos[tid] = 0.f; rneg[tid] = 0.f; cpos[tid] = 0.f; cneg[tid] = 0.f;
  }
  __syncthreads();

  int cl[4], jg[4], lv[4], lj[4];
  float cs[4];
#pragma unroll
  for (int ni = 0; ni < 4; ++ni) {
    cl[ni] = wcbase + ni * 16 + llo;
    jg[ni] = colj[cl[ni]];
    lv[ni] = coll[cl[ni]];
    lj[ni] = collab[cl[ni]];
    cs[ni] = cnorm[cl[ni]];
  }
  float cpAcc[4] = {}, cnAcc[4] = {};
#pragma unroll
  for (int mi = 0; mi < 8; ++mi) {
#pragma unroll
    for (int r = 0; r < 4; ++r) {
      int rl = wrbase + mi * 16 + lhi * 4 + r;
      int ig = i0 + rl;
      int li = rowlab[rl];
      float rscale = rnorm[rl];
      float rp = 0.f, rn = 0.f;
#pragma unroll
      for (int ni = 0; ni < 4; ++ni) {
        float e = __expf(acc[mi][ni][r] * rscale * cs[ni]);
        bool same = (li == lj[ni]);
        bool diag = (ig == jg[ni]);
        if (same) {
          if (!diag && lv[ni] == li) { rp += e; cpAcc[ni] += e; }
        } else {
          rn += e;
          if (lv[ni] == lj[ni]) cnAcc[ni] += e;
        }
      }
      if (rp != 0.f) atomicAdd(&rpos[rl], rp);
      if (rn != 0.f) atomicAdd(&rneg[rl], rn);
    }
  }
#pragma unroll
  for (int ni = 0; ni < 4; ++ni) {
    if (cpAcc[ni] != 0.f) atomicAdd(&cpos[cl[ni]], cpAcc[ni]);
    if (cnAcc[ni] != 0.f) atomicAdd(&cneg[cl[ni]], cnAcc[ni]);
  }
  __syncthreads();
  if (tid < 256) {
    float v;
    v = rpos[tid]; if (v != 0.f) atomicAdd(&pos_z[i0 + tid], v);
    v = rneg[tid]; if (v != 0.f) atomicAdd(&neg_z[i0 + tid], v);
    int j = colj[tid];
    v = cpos[tid]; if (v != 0.f) atomicAdd(&pos_t[j], v);
    v = cneg[tid]; if (v != 0.f) atomicAdd(&neg_t[j], v);
  }
}

// ---------- K8: final loss ----------
__global__ __launch_bounds__(256) void loss_kernel(
    const float* __restrict__ pos_z, const float* __restrict__ neg_z,
    const float* __restrict__ pos_t, const float* __restrict__ neg_t,
    const int* __restrict__ labels, const int* __restrict__ cnt,
    float* __restrict__ out_loss) {
  __shared__ float sbuf[4];
  int i = blockIdx.x * 256 + threadIdx.x;
  float term = 0.f;
  int li = labels[i];
  if (cnt[li] > 1) {
    float pz = pos_z[i], nz = neg_z[i];
    float pt = pos_t[i], nt = neg_t[i];
    term = -logf(pz / (pz + nz + 1e-8f)) - logf(pt / (pt + nt + 1e-8f));
  }
  float s = block_reduce_sum256(term, sbuf);
  if (threadIdx.x == 0) atomicAdd(out_loss, s * (1.0f / B_N));
}

// ---------- launch ----------
extern "C" void kernel_launch(void* const* d_in, const int* in_sizes, int n_in,
                              void* d_out, int out_size, void* d_ws, size_t ws_size,
                              hipStream_t stream) {
  const float* seq = (const float*)d_in[0];
  const float* cls_gamma = (const float*)d_in[1];
  const float* cls_beta = (const float*)d_in[2];
  const float* cls_W = (const float*)d_in[3];
  const float* cls_b = (const float*)d_in[4];
  const float* label_gamma = (const float*)d_in[5];
  const float* label_beta = (const float*)d_in[6];
  const float* label_W = (const float*)d_in[7];
  const float* label_b = (const float*)d_in[8];
  const int* labels = (const int*)d_in[9];
  float* out = (float*)d_out;
  float* ws = (float*)d_ws;

  constexpr size_t OFF_SUMZ = 0;
  constexpr size_t OFF_SSQZ = 768;
  constexpr size_t OFF_SUMT = 1536;
  constexpr size_t OFF_SSQT = 2304;
  constexpr size_t OFF_POSZ = 3072;
  constexpr size_t OFF_NEGZ = 7168;
  constexpr size_t OFF_POST = 11264;
  constexpr size_t OFF_NEGT = 15360;
  constexpr size_t OFF_CNT = 19456;  // 8 ints
  constexpr size_t ZERO_FLOATS = 19464;
  constexpr size_t OFF_SZS = 19464;
  constexpr size_t OFF_SZT = 20232;
  constexpr size_t OFF_STS = 21000;
  constexpr size_t OFF_STT = 21768;
  constexpr size_t OFF_ZNI = 22536;     // 4096
  constexpr size_t OFF_TNI = 26632;     // 20480
  constexpr size_t OFF_CPRIME = 47112;  // 768
  constexpr size_t OFF_ZP = 47880;      // 4096*768 fp32
  constexpr size_t OFF_U = OFF_ZP + (size_t)B_N * H_N;
  constexpr size_t F32_END = OFF_U + (size_t)B_N * H_N;
  constexpr size_t BYTE_ZB = F32_END * sizeof(float);
  constexpr size_t BYTE_TB = BYTE_ZB + (size_t)B_N * H_N * 2;
  constexpr size_t BYTE_ZPB = BYTE_TB + (size_t)B_N * L_N * H_N * 2;
  constexpr size_t BYTE_WCB = BYTE_ZPB + (size_t)B_N * H_N * 2;
  constexpr size_t BYTE_WLT = BYTE_WCB + (size_t)H_N * H_N * 2;
  constexpr size_t TOTAL_BYTES = BYTE_WLT + (size_t)H_N * H_N * 2;
  if (ws_size < TOTAL_BYTES) return;

  __hip_bfloat16* zb = (__hip_bfloat16*)((char*)d_ws + BYTE_ZB);
  __hip_bfloat16* tb = (__hip_bfloat16*)((char*)d_ws + BYTE_TB);
  __hip_bfloat16* zpb = (__hip_bfloat16*)((char*)d_ws + BYTE_ZPB);
  __hip_bfloat16* wcb = (__hip_bfloat16*)((char*)d_ws + BYTE_WCB);
  __hip_bfloat16* wlt = (__hip_bfloat16*)((char*)d_ws + BYTE_WLT);

  hipMemsetAsync(d_ws, 0, ZERO_FLOATS * sizeof(float), stream);
  hipMemsetAsync((char*)d_out + (size_t)B_N * L_N * sizeof(float), 0, sizeof(float),
                 stream);

  extract_kernel<<<256, 256, 0, stream>>>(seq, zb, tb, ws + OFF_ZNI, ws + OFF_TNI,
                                          ws + OFF_SUMZ, ws + OFF_SSQZ,
                                          ws + OFF_SUMT, ws + OFF_SSQT);
  count_kernel<<<16, 256, 0, stream>>>(labels, (int*)(ws + OFF_CNT));
  finalize_kernel<<<3, 256, 0, stream>>>(
      ws + OFF_SUMZ, ws + OFF_SSQZ, ws + OFF_SUMT, ws + OFF_SSQT, cls_gamma,
      cls_beta, label_gamma, label_beta, ws + OFF_SZS, ws + OFF_SZT, ws + OFF_STS,
      ws + OFF_STT);
  prep_cls_kernel<<<H_N, 256, 0, stream>>>(cls_W, ws + OFF_SZS, ws + OFF_SZT, cls_b,
                                           wcb, ws + OFF_CPRIME);
  transpose_wl_kernel<<<dim3(24, 24), 256, 0, stream>>>(label_W, wlt);
  gemm128_kernel<true, true><<<dim3(32, 6), 256, 0, stream>>>(
      zb, wcb, ws + OFF_CPRIME, ws + OFF_ZP, zpb);
  gemm128_kernel<false, false><<<dim3(32, 6), 256, 0, stream>>>(
      zpb, wlt, nullptr, ws + OFF_U, nullptr);
  logits_kernel<<<B_N, 256, 0, stream>>>(seq, ws + OFF_U, ws + OFF_ZP, ws + OFF_STS,
                                         ws + OFF_STT, label_b, out);
  sgemm_fused_kernel<<<dim3(16, 80), 512, 0, stream>>>(
      zb, tb, ws + OFF_ZNI, ws + OFF_TNI, labels, ws + OFF_POSZ, ws + OFF_NEGZ,
      ws + OFF_POST, ws + OFF_NEGT);
  loss_kernel<<<16, 256, 0, stream>>>(ws + OFF_POSZ, ws + OFF_NEGZ, ws + OFF_POST,
                                      ws + OFF_NEGT, labels,
                                      (const int*)(ws + OFF_CNT),
                                      out + (size_t)B_N * L_N);
}

// Round 5
// 455.946 us; speedup vs baseline: 4.7617x; 1.0289x over previous
//
#include <hip/hip_runtime.h>
#include <hip/hip_bf16.h>
#include <cstdint>
#include <cstddef>

#define B_N 4096
#define S_N 64
#define H_N 768
#define L_N 5
#define TEMP_INV (1.0f / 0.07f)
#define BN_EPS 1e-5f

typedef __attribute__((ext_vector_type(8))) short short8;
typedef __attribute__((ext_vector_type(4))) float f32x4;

// ---------- async global->LDS 16B ----------
__device__ __forceinline__ void async_copy16(void* lds, const void* g) {
  __builtin_amdgcn_global_load_lds(
      (const __attribute__((address_space(1))) unsigned int*)g,
      (__attribute__((address_space(3))) unsigned int*)lds, 16, 0, 0);
}

__device__ __forceinline__ unsigned short bf16b(float x) {
  __hip_bfloat16 h = __float2bfloat16(x);
  return *reinterpret_cast<unsigned short*>(&h);
}
__device__ __forceinline__ void store_bf16x4(void* p, float4 v) {
  ushort4 o = make_ushort4(bf16b(v.x), bf16b(v.y), bf16b(v.z), bf16b(v.w));
  *reinterpret_cast<ushort4*>(p) = o;
}

// ---------- block reduction (256 threads = 4 waves) ----------
__device__ inline float block_reduce_sum256(float v, float* sbuf) {
#pragma unroll
  for (int off = 32; off > 0; off >>= 1) v += __shfl_down(v, off, 64);
  int lane = threadIdx.x & 63;
  int wid = threadIdx.x >> 6;
  __syncthreads();
  if (lane == 0) sbuf[wid] = v;
  __syncthreads();
  float r = 0.f;
  if (threadIdx.x == 0) r = sbuf[0] + sbuf[1] + sbuf[2] + sbuf[3];
  return r;  // valid on thread 0 only
}

// ---------- K1: fused extract + row norms + column stats (single seq pass) ----------
__global__ __launch_bounds__(256) void extract_kernel(
    const float* __restrict__ seq, __hip_bfloat16* __restrict__ zb,
    __hip_bfloat16* __restrict__ tb, float* __restrict__ zn_inv,
    float* __restrict__ thn_inv, float* __restrict__ sum_z,
    float* __restrict__ ssq_z, float* __restrict__ sum_t,
    float* __restrict__ ssq_t) {
  __shared__ float pr[16][6][3];  // row, {z,l0..l4}, wave
  int t = threadIdx.x;
  int wv = t >> 6, ln = t & 63;
  bool act = t < 192;
  int c4 = t * 4;
  int b0 = blockIdx.x * 16;
  float zs[4] = {}, zq[4] = {}, ts4[4] = {}, tq4[4] = {};
  for (int r = 0; r < 16; ++r) {
    int b = b0 + r;
    const float* base = seq + (size_t)b * (S_N * H_N);
    float pv[6] = {0.f, 0.f, 0.f, 0.f, 0.f, 0.f};
    if (act) {
      float4 z4 = *(const float4*)(base + c4);
      store_bf16x4(zb + (size_t)b * H_N + c4, z4);
      pv[0] = z4.x * z4.x + z4.y * z4.y + z4.z * z4.z + z4.w * z4.w;
      zs[0] += z4.x; zs[1] += z4.y; zs[2] += z4.z; zs[3] += z4.w;
      zq[0] += z4.x * z4.x; zq[1] += z4.y * z4.y;
      zq[2] += z4.z * z4.z; zq[3] += z4.w * z4.w;
#pragma unroll
      for (int l = 0; l < L_N; ++l) {
        float4 v4;
        if (l == 0) {
          float4 a4 = *(const float4*)(base + H_N + c4);
          float4 b4 = *(const float4*)(base + 2 * H_N + c4);
          v4 = make_float4(0.5f * (a4.x + b4.x), 0.5f * (a4.y + b4.y),
                           0.5f * (a4.z + b4.z), 0.5f * (a4.w + b4.w));
        } else {
          v4 = *(const float4*)(base + (size_t)(l + 2) * H_N + c4);
        }
        store_bf16x4(tb + ((size_t)b * L_N + l) * H_N + c4, v4);
        pv[1 + l] = v4.x * v4.x + v4.y * v4.y + v4.z * v4.z + v4.w * v4.w;
        ts4[0] += v4.x; ts4[1] += v4.y; ts4[2] += v4.z; ts4[3] += v4.w;
        tq4[0] += v4.x * v4.x; tq4[1] += v4.y * v4.y;
        tq4[2] += v4.z * v4.z; tq4[3] += v4.w * v4.w;
      }
    }
#pragma unroll
    for (int v = 0; v < 6; ++v) {
      float x = pv[v];
#pragma unroll
      for (int off = 32; off > 0; off >>= 1) x += __shfl_down(x, off, 64);
      if (ln == 0 && wv < 3) pr[r][v][wv] = x;
    }
  }
  __syncthreads();
  if (t < 96) {
    int r = t / 6, v = t - r * 6;
    float s = pr[r][v][0] + pr[r][v][1] + pr[r][v][2];
    float inv = 1.f / fmaxf(sqrtf(s), 1e-12f);
    int b = b0 + r;
    if (v == 0) zn_inv[b] = inv;
    else thn_inv[b * L_N + (v - 1)] = inv;
  }
  if (act) {
#pragma unroll
    for (int j = 0; j < 4; ++j) {
      atomicAdd(&sum_z[c4 + j], zs[j]);
      atomicAdd(&ssq_z[c4 + j], zq[j]);
      atomicAdd(&sum_t[c4 + j], ts4[j]);
      atomicAdd(&ssq_t[c4 + j], tq4[j]);
    }
  }
}

// ---------- label histogram ----------
__global__ void count_kernel(const int* __restrict__ labels, int* __restrict__ cnt) {
  int i = blockIdx.x * 256 + threadIdx.x;
  if (i < B_N) atomicAdd(&cnt[labels[i]], 1);
}

// ---------- K3: bn affine coefficients ----------
__global__ void finalize_kernel(
    const float* __restrict__ sum_z, const float* __restrict__ ssq_z,
    const float* __restrict__ sum_t, const float* __restrict__ ssq_t,
    const float* __restrict__ g_z, const float* __restrict__ b_z,
    const float* __restrict__ g_t, const float* __restrict__ b_t,
    float* __restrict__ sz_s, float* __restrict__ sz_t,
    float* __restrict__ st_s, float* __restrict__ st_t) {
  int h = blockIdx.x * 256 + threadIdx.x;
  if (h >= H_N) return;
  {
    float m = sum_z[h] * (1.f / B_N);
    float v = ssq_z[h] * (1.f / B_N) - m * m;
    float s = g_z[h] * rsqrtf(v + BN_EPS);
    sz_s[h] = s;
    sz_t[h] = b_z[h] - m * s;
  }
  {
    float m = sum_t[h] * (1.f / (B_N * L_N));
    float v = ssq_t[h] * (1.f / (B_N * L_N)) - m * m;
    float s = g_t[h] * rsqrtf(v + BN_EPS);
    st_s[h] = s;
    st_t[h] = b_t[h] - m * s;
  }
}

// ---------- K3b: fold BN scale into cls_W (bf16) + folded bias ----------
__global__ __launch_bounds__(256) void prep_cls_kernel(
    const float* __restrict__ W, const float* __restrict__ szs,
    const float* __restrict__ szt, const float* __restrict__ bias,
    __hip_bfloat16* __restrict__ Wb, float* __restrict__ cprime) {
  __shared__ float sbuf[4];
  int n = blockIdx.x;
  int t = threadIdx.x;
  float dot = 0.f;
  if (t < 192) {
    int c4 = t * 4;
    const float* row = W + (size_t)n * H_N;
    float4 w4 = *(const float4*)(row + c4);
    float4 s4 = *(const float4*)(szs + c4);
    float4 t4 = *(const float4*)(szt + c4);
    store_bf16x4(Wb + (size_t)n * H_N + c4,
                 make_float4(w4.x * s4.x, w4.y * s4.y, w4.z * s4.z, w4.w * s4.w));
    dot = w4.x * t4.x + w4.y * t4.y + w4.z * t4.z + w4.w * t4.w;
  }
  float s = block_reduce_sum256(dot, sbuf);
  if (t == 0) cprime[n] = s + bias[n];
}

// ---------- K3c: WlT[k][n] = bf16(label_W[n][k]) ----------
__global__ __launch_bounds__(256) void transpose_wl_kernel(
    const float* __restrict__ Wl, __hip_bfloat16* __restrict__ WlT) {
  __shared__ float tile[32][33];
  int t = threadIdx.x;
  int tx = t & 31, ty0 = t >> 5;
  int n0 = blockIdx.x * 32, k0 = blockIdx.y * 32;
#pragma unroll
  for (int p = 0; p < 4; ++p)
    tile[ty0 + p * 8][tx] = Wl[(size_t)(n0 + ty0 + p * 8) * H_N + k0 + tx];
  __syncthreads();
#pragma unroll
  for (int p = 0; p < 4; ++p) {
    unsigned short us = bf16b(tile[tx][ty0 + p * 8]);
    *((unsigned short*)WlT + (size_t)(k0 + ty0 + p * 8) * H_N + n0 + tx) = us;
  }
}

// ---------- K4/K5: 128x128 bf16 MFMA GEMM template ----------
template <bool WRITE_BF16, bool HAS_BIAS>
__global__ __launch_bounds__(256) void gemm128_kernel(
    const __hip_bfloat16* __restrict__ A, const __hip_bfloat16* __restrict__ Bm,
    const float* __restrict__ bias, float* __restrict__ outF,
    __hip_bfloat16* __restrict__ outB) {
  __shared__ __align__(16) __hip_bfloat16 Asm[128 * 32];
  __shared__ __align__(16) __hip_bfloat16 Bsm[128 * 32];
  int tid = threadIdx.x, lane = tid & 63, wid = tid >> 6;
  int wr = wid >> 1, wc = wid & 1;
  int i0 = blockIdx.x * 128, n0 = blockIdx.y * 128;
  int llo = lane & 15, lhi = lane >> 4;
  f32x4 acc[4][4] = {};
  for (int k0 = 0; k0 < H_N; k0 += 32) {
#pragma unroll
    for (int r = 0; r < 2; ++r) {
      int s = r * 256 + wid * 64 + lane;
      int row = s >> 2, kc = (s & 3) * 8;
      size_t go = (size_t)row * H_N + k0 + kc;
      async_copy16((char*)Asm + (size_t)(r * 256 + wid * 64) * 16,
                   A + (size_t)i0 * H_N + go);
      async_copy16((char*)Bsm + (size_t)(r * 256 + wid * 64) * 16,
                   Bm + (size_t)n0 * H_N + go);
    }
    __syncthreads();
    short8 a[4], b[4];
#pragma unroll
    for (int m = 0; m < 4; ++m)
      a[m] = *(const short8*)((const char*)Asm +
                              ((wr * 64 + m * 16 + llo) * 32 + lhi * 8) * 2);
#pragma unroll
    for (int n = 0; n < 4; ++n)
      b[n] = *(const short8*)((const char*)Bsm +
                              ((wc * 64 + n * 16 + llo) * 32 + lhi * 8) * 2);
#pragma unroll
    for (int m = 0; m < 4; ++m)
#pragma unroll
      for (int n = 0; n < 4; ++n)
        acc[m][n] =
            __builtin_amdgcn_mfma_f32_16x16x32_bf16(a[m], b[n], acc[m][n], 0, 0, 0);
    __syncthreads();
  }
#pragma unroll
  for (int n = 0; n < 4; ++n) {
    int col = n0 + wc * 64 + n * 16 + llo;
    float bv = HAS_BIAS ? bias[col] : 0.f;
#pragma unroll
    for (int m = 0; m < 4; ++m) {
#pragma unroll
      for (int r = 0; r < 4; ++r) {
        int row = i0 + wr * 64 + m * 16 + lhi * 4 + r;
        float val = acc[m][n][r] + bv;
        outF[(size_t)row * H_N + col] = val;
        if (WRITE_BF16)
          outB[(size_t)row * H_N + col] = __float2bfloat16(val);
      }
    }
  }
}

// ---------- K6: logits ----------
__global__ __launch_bounds__(256) void logits_kernel(
    const float* __restrict__ seq, const float* __restrict__ u,
    const float* __restrict__ zp, const float* __restrict__ st_s,
    const float* __restrict__ st_t, const float* __restrict__ label_b,
    float* __restrict__ out) {
  __shared__ float sbuf[4];
  int b = blockIdx.x;
  int t = threadIdx.x;
  bool act = t < 192;
  int c4 = t * 4;
  float4 w4 = make_float4(0.f, 0.f, 0.f, 0.f);
  float apart = 0.f;
  if (act) {
    float4 u4 = *(const float4*)(u + (size_t)b * H_N + c4);
    float4 zp4 = *(const float4*)(zp + (size_t)b * H_N + c4);
    float4 ss4 = *(const float4*)(st_s + c4);
    float4 tt4 = *(const float4*)(st_t + c4);
    float4 lb4 = *(const float4*)(label_b + c4);
    w4 = make_float4(u4.x * ss4.x, u4.y * ss4.y, u4.z * ss4.z, u4.w * ss4.w);
    apart = u4.x * tt4.x + u4.y * tt4.y + u4.z * tt4.z + u4.w * tt4.w +
            zp4.x * lb4.x + zp4.y * lb4.y + zp4.z * lb4.z + zp4.w * lb4.w;
  }
  float alpha = block_reduce_sum256(apart, sbuf);
  const float* base = seq + (size_t)b * (S_N * H_N);
#pragma unroll
  for (int l = 0; l < L_N; ++l) {
    float part = 0.f;
    if (act) {
      float4 v4;
      if (l == 0) {
        float4 a4 = *(const float4*)(base + H_N + c4);
        float4 b4 = *(const float4*)(base + 2 * H_N + c4);
        v4 = make_float4(0.5f * (a4.x + b4.x), 0.5f * (a4.y + b4.y),
                         0.5f * (a4.z + b4.z), 0.5f * (a4.w + b4.w));
      } else {
        v4 = *(const float4*)(base + (size_t)(l + 2) * H_N + c4);
      }
      part = v4.x * w4.x + v4.y * w4.y + v4.z * w4.z + v4.w * w4.w;
    }
    float s = block_reduce_sum256(part, sbuf);
    if (t == 0) out[b * L_N + l] = s + alpha;
  }
}

// ---------- K7: 256x256 8-wave bf16 MFMA GEMM, per-phase interleaved pipeline ----------
// 4 phases per K-tile: {8 ds_read (quadrant) || 2 global_load_lds (part p of
// tile t+1, other buffer) -> barrier -> lgkmcnt(0)+sched_barrier -> 16 MFMA ->
// barrier}; vmcnt(0) only at the K-tile boundary (loads have ~3 phases in
// flight by then). XOR swizzle both-sides (rule #21), carried from R4.
#define NT_K 12  // 768 / 64
__global__ __launch_bounds__(512, 1) void sgemm_fused_kernel(
    const __hip_bfloat16* __restrict__ zb, const __hip_bfloat16* __restrict__ tb,
    const float* __restrict__ zn_inv, const float* __restrict__ thn_inv,
    const int* __restrict__ labels, float* __restrict__ pos_z,
    float* __restrict__ neg_z, float* __restrict__ pos_t,
    float* __restrict__ neg_t) {
  __shared__ __align__(128) char ldsbuf[2][65536];  // per buf: A 32KB | B 32KB

  const int tid = threadIdx.x;
  const int lane = tid & 63, wid = tid >> 6;
  const int llo = lane & 15, lhi = lane >> 4;
  const int wrbase = (wid >> 2) * 128;  // 2 wave-rows
  const int wcbase = (wid & 3) * 64;    // 4 wave-cols
  const int i0 = blockIdx.x * 256, n0 = blockIdx.y * 256;

  f32x4 acc[8][4] = {};

  // stage row-part p (64 rows x 64 k) of K-tile kt for A and B into buffer c
  auto stagePart = [&](int c, int kt, int p) {
    int s = p * 512 + tid;
    int row = s >> 3;                // 8 x 16B slots per 128B row
    int lq = (s & 7) ^ (row & 7);    // inverse swizzle on global source
    int kofs = kt * 64 + lq * 8;
    int wub = (p * 512 + wid * 64) * 16;  // wave-uniform LDS base
    async_copy16(&ldsbuf[c][0] + wub, zb + (size_t)(i0 + row) * H_N + kofs);
    async_copy16(&ldsbuf[c][32768] + wub, tb + (size_t)(n0 + row) * H_N + kofs);
  };

  // prologue: stage K-tile 0 fully, drain, publish
#pragma unroll
  for (int p = 0; p < 4; ++p) stagePart(0, 0, p);
  asm volatile("s_waitcnt vmcnt(0)" ::: "memory");
  __builtin_amdgcn_s_barrier();

  for (int t = 0; t < NT_K; ++t) {
    const char* ldsA = &ldsbuf[t & 1][0];
    const char* ldsB = &ldsbuf[t & 1][32768];
#pragma unroll
    for (int p = 0; p < 4; ++p) {
      const int kk = p >> 1, mh = (p & 1) * 4;
      const int slot = ((kk * 4 + lhi) ^ (llo & 7)) * 16;  // swizzled read
      short8 a[4], b[4];
#pragma unroll
      for (int m = 0; m < 4; ++m) {
        int row = wrbase + (mh + m) * 16 + llo;
        a[m] = *(const short8*)(ldsA + row * 128 + slot);
      }
#pragma unroll
      for (int n = 0; n < 4; ++n) {
        int col = wcbase + n * 16 + llo;
        b[n] = *(const short8*)(ldsB + col * 128 + slot);
      }
      if (t + 1 < NT_K) stagePart((t + 1) & 1, t + 1, p);  // fly across phases
      __builtin_amdgcn_s_barrier();
      asm volatile("s_waitcnt lgkmcnt(0)" ::: "memory");
      __builtin_amdgcn_sched_barrier(0);  // rule #18: pin MFMA below the wait
      __builtin_amdgcn_s_setprio(1);
#pragma unroll
      for (int m = 0; m < 4; ++m)
#pragma unroll
        for (int n = 0; n < 4; ++n)
          acc[mh + m][n] = __builtin_amdgcn_mfma_f32_16x16x32_bf16(
              a[m], b[n], acc[mh + m][n], 0, 0, 0);
      __builtin_amdgcn_s_setprio(0);
      if (p == 3)  // K-tile boundary: next tile must be resident after barrier
        asm volatile("s_waitcnt vmcnt(0)" ::: "memory");
      __builtin_amdgcn_s_barrier();
    }
  }
  __syncthreads();  // full fence before overlaying epilogue arrays onto ldsbuf

  // ---- fused epilogue: exp + masks + row/col reductions (LDS overlay) ----
  float* rpos = (float*)&ldsbuf[0][0];
  float* rneg = rpos + 256;
  float* cpos = rneg + 256;
  float* cneg = cpos + 256;
  float* rnorm = cneg + 256;
  float* cnorm = rnorm + 256;
  int* rowlab = (int*)(cnorm + 256);
  int* colj = rowlab + 256;
  int* coll = colj + 256;
  int* collab = coll + 256;

  if (tid < 256) {
    rowlab[tid] = labels[i0 + tid];
    rnorm[tid] = zn_inv[i0 + tid] * TEMP_INV;
    int c = n0 + tid;
    int j = c / 5;
    colj[tid] = j;
    coll[tid] = c - j * 5;
    collab[tid] = labels[j];
    cnorm[tid] = thn_inv[c];
    rpos[tid] = 0.f; rneg[tid] = 0.f; cpos[tid] = 0.f; cneg[tid] = 0.f;
  }
  __syncthreads();

  int cl[4], jg[4], lv[4], lj[4];
  float cs[4];
#pragma unroll
  for (int ni = 0; ni < 4; ++ni) {
    cl[ni] = wcbase + ni * 16 + llo;
    jg[ni] = colj[cl[ni]];
    lv[ni] = coll[cl[ni]];
    lj[ni] = collab[cl[ni]];
    cs[ni] = cnorm[cl[ni]];
  }
  float cpAcc[4] = {}, cnAcc[4] = {};
#pragma unroll
  for (int mi = 0; mi < 8; ++mi) {
#pragma unroll
    for (int r = 0; r < 4; ++r) {
      int rl = wrbase + mi * 16 + lhi * 4 + r;
      int ig = i0 + rl;
      int li = rowlab[rl];
      float rscale = rnorm[rl];
      float rp = 0.f, rn = 0.f;
#pragma unroll
      for (int ni = 0; ni < 4; ++ni) {
        float e = __expf(acc[mi][ni][r] * rscale * cs[ni]);
        bool same = (li == lj[ni]);
        bool diag = (ig == jg[ni]);
        if (same) {
          if (!diag && lv[ni] == li) { rp += e; cpAcc[ni] += e; }
        } else {
          rn += e;
          if (lv[ni] == lj[ni]) cnAcc[ni] += e;
        }
      }
      if (rp != 0.f) atomicAdd(&rpos[rl], rp);
      if (rn != 0.f) atomicAdd(&rneg[rl], rn);
    }
  }
#pragma unroll
  for (int ni = 0; ni < 4; ++ni) {
    if (cpAcc[ni] != 0.f) atomicAdd(&cpos[cl[ni]], cpAcc[ni]);
    if (cnAcc[ni] != 0.f) atomicAdd(&cneg[cl[ni]], cnAcc[ni]);
  }
  __syncthreads();
  if (tid < 256) {
    float v;
    v = rpos[tid]; if (v != 0.f) atomicAdd(&pos_z[i0 + tid], v);
    v = rneg[tid]; if (v != 0.f) atomicAdd(&neg_z[i0 + tid], v);
    int j = colj[tid];
    v = cpos[tid]; if (v != 0.f) atomicAdd(&pos_t[j], v);
    v = cneg[tid]; if (v != 0.f) atomicAdd(&neg_t[j], v);
  }
}

// ---------- K8: final loss ----------
__global__ __launch_bounds__(256) void loss_kernel(
    const float* __restrict__ pos_z, const float* __restrict__ neg_z,
    const float* __restrict__ pos_t, const float* __restrict__ neg_t,
    const int* __restrict__ labels, const int* __restrict__ cnt,
    float* __restrict__ out_loss) {
  __shared__ float sbuf[4];
  int i = blockIdx.x * 256 + threadIdx.x;
  float term = 0.f;
  int li = labels[i];
  if (cnt[li] > 1) {
    float pz = pos_z[i], nz = neg_z[i];
    float pt = pos_t[i], nt = neg_t[i];
    term = -logf(pz / (pz + nz + 1e-8f)) - logf(pt / (pt + nt + 1e-8f));
  }
  float s = block_reduce_sum256(term, sbuf);
  if (threadIdx.x == 0) atomicAdd(out_loss, s * (1.0f / B_N));
}

// ---------- launch ----------
extern "C" void kernel_launch(void* const* d_in, const int* in_sizes, int n_in,
                              void* d_out, int out_size, void* d_ws, size_t ws_size,
                              hipStream_t stream) {
  const float* seq = (const float*)d_in[0];
  const float* cls_gamma = (const float*)d_in[1];
  const float* cls_beta = (const float*)d_in[2];
  const float* cls_W = (const float*)d_in[3];
  const float* cls_b = (const float*)d_in[4];
  const float* label_gamma = (const float*)d_in[5];
  const float* label_beta = (const float*)d_in[6];
  const float* label_W = (const float*)d_in[7];
  const float* label_b = (const float*)d_in[8];
  const int* labels = (const int*)d_in[9];
  float* out = (float*)d_out;
  float* ws = (float*)d_ws;

  constexpr size_t OFF_SUMZ = 0;
  constexpr size_t OFF_SSQZ = 768;
  constexpr size_t OFF_SUMT = 1536;
  constexpr size_t OFF_SSQT = 2304;
  constexpr size_t OFF_POSZ = 3072;
  constexpr size_t OFF_NEGZ = 7168;
  constexpr size_t OFF_POST = 11264;
  constexpr size_t OFF_NEGT = 15360;
  constexpr size_t OFF_CNT = 19456;  // 8 ints
  constexpr size_t ZERO_FLOATS = 19464;
  constexpr size_t OFF_SZS = 19464;
  constexpr size_t OFF_SZT = 20232;
  constexpr size_t OFF_STS = 21000;
  constexpr size_t OFF_STT = 21768;
  constexpr size_t OFF_ZNI = 22536;     // 4096
  constexpr size_t OFF_TNI = 26632;     // 20480
  constexpr size_t OFF_CPRIME = 47112;  // 768
  constexpr size_t OFF_ZP = 47880;      // 4096*768 fp32
  constexpr size_t OFF_U = OFF_ZP + (size_t)B_N * H_N;
  constexpr size_t F32_END = OFF_U + (size_t)B_N * H_N;
  constexpr size_t BYTE_ZB = F32_END * sizeof(float);
  constexpr size_t BYTE_TB = BYTE_ZB + (size_t)B_N * H_N * 2;
  constexpr size_t BYTE_ZPB = BYTE_TB + (size_t)B_N * L_N * H_N * 2;
  constexpr size_t BYTE_WCB = BYTE_ZPB + (size_t)B_N * H_N * 2;
  constexpr size_t BYTE_WLT = BYTE_WCB + (size_t)H_N * H_N * 2;
  constexpr size_t TOTAL_BYTES = BYTE_WLT + (size_t)H_N * H_N * 2;
  if (ws_size < TOTAL_BYTES) return;

  __hip_bfloat16* zb = (__hip_bfloat16*)((char*)d_ws + BYTE_ZB);
  __hip_bfloat16* tb = (__hip_bfloat16*)((char*)d_ws + BYTE_TB);
  __hip_bfloat16* zpb = (__hip_bfloat16*)((char*)d_ws + BYTE_ZPB);
  __hip_bfloat16* wcb = (__hip_bfloat16*)((char*)d_ws + BYTE_WCB);
  __hip_bfloat16* wlt = (__hip_bfloat16*)((char*)d_ws + BYTE_WLT);

  hipMemsetAsync(d_ws, 0, ZERO_FLOATS * sizeof(float), stream);
  hipMemsetAsync((char*)d_out + (size_t)B_N * L_N * sizeof(float), 0, sizeof(float),
                 stream);

  extract_kernel<<<256, 256, 0, stream>>>(seq, zb, tb, ws + OFF_ZNI, ws + OFF_TNI,
                                          ws + OFF_SUMZ, ws + OFF_SSQZ,
                                          ws + OFF_SUMT, ws + OFF_SSQT);
  count_kernel<<<16, 256, 0, stream>>>(labels, (int*)(ws + OFF_CNT));
  finalize_kernel<<<3, 256, 0, stream>>>(
      ws + OFF_SUMZ, ws + OFF_SSQZ, ws + OFF_SUMT, ws + OFF_SSQT, cls_gamma,
      cls_beta, label_gamma, label_beta, ws + OFF_SZS, ws + OFF_SZT, ws + OFF_STS,
      ws + OFF_STT);
  prep_cls_kernel<<<H_N, 256, 0, stream>>>(cls_W, ws + OFF_SZS, ws + OFF_SZT, cls_b,
                                           wcb, ws + OFF_CPRIME);
  transpose_wl_kernel<<<dim3(24, 24), 256, 0, stream>>>(label_W, wlt);
  gemm128_kernel<true, true><<<dim3(32, 6), 256, 0, stream>>>(
      zb, wcb, ws + OFF_CPRIME, ws + OFF_ZP, zpb);
  gemm128_kernel<false, false><<<dim3(32, 6), 256, 0, stream>>>(
      zpb, wlt, nullptr, ws + OFF_U, nullptr);
  logits_kernel<<<B_N, 256, 0, stream>>>(seq, ws + OFF_U, ws + OFF_ZP, ws + OFF_STS,
                                         ws + OFF_STT, label_b, out);
  sgemm_fused_kernel<<<dim3(16, 80), 512, 0, stream>>>(
      zb, tb, ws + OFF_ZNI, ws + OFF_TNI, labels, ws + OFF_POSZ, ws + OFF_NEGZ,
      ws + OFF_POST, ws + OFF_NEGT);
  loss_kernel<<<16, 256, 0, stream>>>(ws + OFF_POSZ, ws + OFF_NEGZ, ws + OFF_POST,
                                      ws + OFF_NEGT, labels,
                                      (const int*)(ws + OFF_CNT),
                                      out + (size_t)B_N * L_N);
}